// Round 8
// baseline (2083.619 us; speedup 1.0000x reference)
//
#include <hip/hip_runtime.h>
#include <math.h>

#define BD 8
#define ND 1024
#define KNN 20
#define NEGS 0.2f
#define BNSC 0.99999500003749969482f
#define KSL 8      // key slices for flash-decode attention
#define KPS 128    // keys per slice

__device__ __forceinline__ float leakyf(float y){ return y >= 0.f ? y : NEGS*y; }

// x buffers (xA/xB) use the knn-tiled layout: x_t[b][g][n][4], g = feature quad.
// ALL per-batch kernels map b = blockIdx.x & 7: batch-per-XCD L2 affinity (r7:
// FETCH 16.7->2.2 MB). knn reads columns DIRECTLY from L1/L2 -- no LDS staging, no
// barriers (r7 post-mortem: the stage->barrier->compute structure was ~2/3 of knn
// time; staged tile is 32KB = L1-sized and L2-local => staging is pure overhead,
// m169 lesson. 5 pipelining attempts failed on registers/ordering; removal > hiding).

// -------- fused input slice + transpose + xx: tiled write, b-affinity ----------------
template<int C, int CS>
__global__ __launch_bounds__(256) void k_prep(const float* __restrict__ feat,
                                              float* __restrict__ x,
                                              float* __restrict__ xx, int c0){
  int b = blockIdx.x & 7;
  int n = (blockIdx.x >> 3)*256 + threadIdx.x;
  float v[CS];
  float s = 0.f;
  #pragma unroll
  for (int c = 0; c < C; ++c){
    v[c] = feat[((size_t)(b*15) + c0 + c)*ND + n];
    s = fmaf(v[c], v[c], s);
  }
  #pragma unroll
  for (int c = C; c < CS; ++c) v[c] = 0.f;
  #pragma unroll
  for (int g = 0; g < CS/4; ++g)
    *(float4*)&x[(size_t)(b*CS + g*4)*ND + (size_t)n*4] =
        make_float4(v[g*4], v[g*4+1], v[g*4+2], v[g*4+3]);
  xx[b*ND + n] = s;
}

// -------- fused gram + exact top-20: barrier-free direct-L2 reads --------------------
// block = 16 rows (4 waves x 4 rows), waves fully independent. cv loads are
// 16B/lane wave-contiguous (1024B/instr) from the tiled x: first toucher fills L1,
// the CU's 8 waves hit it; loads pipeline under the FMA stream with counted vmcnt
// (no drain points). Row fragments via wave-uniform loads -> scalar path.
__global__ __launch_bounds__(256)
void k_knn(const float* __restrict__ x,
    const float* __restrict__ xx, int* __restrict__ idxp, int CS, int nchunk){
  int b = blockIdx.x & 7;
  int r0 = (blockIdx.x >> 3)*16;
  int t = threadIdx.x;
  int lane = t & 63;
  int w = __builtin_amdgcn_readfirstlane(t >> 6);   // wave-uniform wave id
  const float* xb = x + (size_t)b*ND*CS;            // tiled [G][n][4]
  float acc[4][16];
  #pragma unroll
  for (int j = 0; j < 4; ++j)
    #pragma unroll
    for (int q = 0; q < 16; ++q) acc[j][q] = 0.f;
  for (int ch = 0; ch < nchunk; ++ch){
    int g0 = 2*ch, g1 = 2*ch + 1;
    bool h1 = (g1*4 < CS);
    const float* cb0 = &xb[(size_t)g0*ND*4];
    const float* cb1 = &xb[(size_t)g1*ND*4];
    // row fragments: wave-uniform global loads (scalar regs)
    float4 rv0[4], rv1[4];
    #pragma unroll
    for (int j = 0; j < 4; ++j){
      rv0[j] = *(const float4*)&cb0[(size_t)(r0 + w*4 + j)*4];
      rv1[j] = h1 ? *(const float4*)&cb1[(size_t)(r0 + w*4 + j)*4]
                  : make_float4(0.f,0.f,0.f,0.f);
    }
    #pragma unroll
    for (int q = 0; q < 16; ++q){
      float4 cv0 = *(const float4*)&cb0[(size_t)(q*64 + lane)*4];
      float4 cv1 = h1 ? *(const float4*)&cb1[(size_t)(q*64 + lane)*4]
                      : make_float4(0.f,0.f,0.f,0.f);
      #pragma unroll
      for (int j = 0; j < 4; ++j){
        float s = acc[j][q];   // strict sequential col order: bitwise-stable result
        s = fmaf(rv0[j].x, cv0.x, s); s = fmaf(rv0[j].y, cv0.y, s);
        s = fmaf(rv0[j].z, cv0.z, s); s = fmaf(rv0[j].w, cv0.w, s);
        s = fmaf(rv1[j].x, cv1.x, s); s = fmaf(rv1[j].y, cv1.y, s);
        s = fmaf(rv1[j].z, cv1.z, s); s = fmaf(rv1[j].w, cv1.w, s);
        acc[j][q] = s;
      }
    }
  }
  // transform to negdist = 2*dot - xx_r - xx_m, then to sortable uints
  float xxm[16];
  #pragma unroll
  for (int q = 0; q < 16; ++q) xxm[q] = xx[b*ND + q*64 + lane];
  unsigned uk[4][16];
  #pragma unroll
  for (int j = 0; j < 4; ++j){
    float xr = xx[b*ND + r0 + w*4 + j];
    #pragma unroll
    for (int q = 0; q < 16; ++q){
      float f = 2.f*acc[j][q] - xr - xxm[q];
      unsigned bv = __float_as_uint(f);
      uk[j][q] = (bv & 0x80000000u) ? ~bv : (bv | 0x80000000u);  // order-preserving
    }
  }
  // radix binary search for T = 20th-largest key per row (bit 31: only the diagonal
  // reaches it, count==1<20 always -> skip). Early exit at exact count==20 (set-equal).
  unsigned pref[4] = {0u, 0u, 0u, 0u};
  unsigned done = 0u;
  #pragma unroll 1
  for (int bit = 30; bit >= 0; --bit){
    #pragma unroll
    for (int u = 0; u < 4; ++u){
      if (done & (1u << u)) continue;           // wave-uniform (ballot-derived)
      unsigned cand = pref[u] | (1u << bit);
      int c = 0;
      #pragma unroll
      for (int q = 0; q < 16; ++q)
        c += (int)__popcll(__ballot(uk[u][q] >= cand));
      if (c >= KNN){
        pref[u] = cand;
        if (c == KNN) done |= (1u << u);
      }
    }
    if (done == 15u) break;
  }
  // emit: all keys > T, plus lowest-global-index keys == T to fill to 20
  unsigned long long mlt = (1ull << lane) - 1ull;   // lanes below me
  #pragma unroll
  for (int u = 0; u < 4; ++u){
    unsigned T = pref[u];
    int cg = 0;
    #pragma unroll
    for (int q = 0; q < 16; ++q) cg += (int)__popcll(__ballot(uk[u][q] > T));
    int need_eq = KNN - cg;                          // >= 1 by construction
    int* op = &idxp[((size_t)(b*ND + r0 + w*4 + u))*KNN];
    int run_gt = 0, run_eq = 0;
    #pragma unroll
    for (int q = 0; q < 16; ++q){
      unsigned k = uk[u][q];
      unsigned long long bg = __ballot(k > T);
      unsigned long long be = __ballot(k == T);
      if (k > T) op[run_gt + (int)__popcll(bg & mlt)] = q*64 + lane;
      if (k == T){
        int r = run_eq + (int)__popcll(be & mlt);
        if (r < need_eq) op[cg + r] = q*64 + lane;
      }
      run_gt += (int)__popcll(bg);
      run_eq += (int)__popcll(be);
    }
  }
}

// ------ phase A (register-blocked), x read from tiled layout, b-affinity -------------
template<int O>
__global__ __launch_bounds__(256) void k_phaseA(const float* __restrict__ x,
    const float* __restrict__ W, const float* __restrict__ bias,
    const float* __restrict__ gamma, const float* __restrict__ beta,
    float* __restrict__ zs, float* __restrict__ ccv, int C, int XS){
  constexpr int TO = O/16;
  constexpr int WP = O + 4;
  __shared__ float W1s[32*WP];
  __shared__ float dWs[32*WP];
  __shared__ float Xs[32*33];
  int blk = blockIdx.x;
  int b = blk & 7, n0 = (blk >> 3)*32;
  int t = threadIdx.x;
  int ot = t & 15, nt = t >> 4;
  int obase = ot*TO;
  int nl = nt*2;
  float az[TO][2] = {}, ac[TO][2] = {};
  for (int cc = 0; cc < C; cc += 32){
    int KC = (C - cc < 32) ? (C - cc) : 32;
    int NG = (KC + 3) >> 2;
    for (int i = t; i < O*KC; i += 256){
      int o = i % O, c = i / O;
      float w1 = W[(size_t)o*2*C + cc + c];
      float w2 = W[(size_t)o*2*C + C + cc + c];
      W1s[c*WP + o] = w1;
      dWs[c*WP + o] = w2 - w1;
    }
    for (int i = t; i < 32*NG; i += 256){
      int row = i & 31, g = i >> 5;
      float4 v = *(const float4*)&x[(size_t)(b*XS + cc + g*4)*ND + (size_t)(n0+row)*4];
      Xs[(g*4+0)*33 + row] = v.x;
      Xs[(g*4+1)*33 + row] = v.y;
      Xs[(g*4+2)*33 + row] = v.z;
      Xs[(g*4+3)*33 + row] = v.w;
    }
    __syncthreads();
    for (int c = 0; c < KC; ++c){
      float xv0 = Xs[c*33 + nl];
      float xv1 = Xs[c*33 + nl + 1];
      #pragma unroll
      for (int i = 0; i < TO; ++i){
        float w1 = W1s[c*WP + obase + i];
        float dw = dWs[c*WP + obase + i];
        az[i][0] = fmaf(w1, xv0, az[i][0]);
        az[i][1] = fmaf(w1, xv1, az[i][1]);
        ac[i][0] = fmaf(dw, xv0, ac[i][0]);
        ac[i][1] = fmaf(dw, xv1, ac[i][1]);
      }
    }
    __syncthreads();
  }
  #pragma unroll
  for (int i = 0; i < TO; ++i){
    int o = obase + i;
    float alpha = gamma[o]*BNSC;
    float bb = bias[o], be = beta[o];
    #pragma unroll
    for (int q = 0; q < 2; ++q){
      int n = n0 + nl + q;
      size_t off = ((size_t)b*ND + n)*O + o;
      zs[off]  = az[i][q]*alpha;
      ccv[off] = fmaf(ac[i][q] + bb, alpha, be);
    }
  }
}

// ------ phase B: out = max_k leaky(zs[idx_k]+cc); TILED knn-layout writes; b-affinity -
template<bool DOXX, bool TILED>
__global__ __launch_bounds__(256) void k_phaseB(const float* __restrict__ zs,
    const float* __restrict__ ccv, const int* __restrict__ idxp,
    float* __restrict__ outp, float* __restrict__ xxout,
    int O, int ostride, int ooff){
  int t = threadIdx.x;
  int lane = t & 63, w = t >> 6;
  int b = blockIdx.x & 7;
  int n = (blockIdx.x >> 3)*4 + w;
  int gn = (b << 10) + n;
  int mm[KNN];
  const int* ip = idxp + (size_t)gn*KNN;
  #pragma unroll
  for (int k = 0; k < KNN; ++k) mm[k] = ip[k];
  float sq = 0.f;
  for (int o = lane; o < O; o += 64){
    float cvv = ccv[(size_t)gn*O + o];
    float mx = -INFINITY;
    #pragma unroll 4
    for (int k = 0; k < KNN; ++k){
      float v = leakyf(zs[((size_t)(b*ND) + mm[k])*O + o] + cvv);
      mx = fmaxf(mx, v);
    }
    if (TILED)
      outp[(size_t)(b*O + (o & ~3))*ND + (size_t)n*4 + (o & 3)] = mx;
    else
      outp[(size_t)gn*ostride + ooff + o] = mx;
    if (DOXX) sq = fmaf(mx, mx, sq);
  }
  if (DOXX){
    #pragma unroll
    for (int off = 32; off; off >>= 1) sq += __shfl_down(sq, off);
    if (lane == 0) xxout[gn] = sq;
  }
}

// --------- qkv[bn,o] = fuse[bn,:].Wi[o,:] + bi[o]  (raw Wi, float4), b-affinity ------
__global__ __launch_bounds__(256) void k_lin(const float* __restrict__ in,
    const float* __restrict__ Wm, const float* __restrict__ bias,
    float* __restrict__ outp){
  int b = blockIdx.x & 7;
  int inner = (blockIdx.x >> 3)*256 + threadIdx.x;   // 0..196607
  int o = inner % 192; int n = inner / 192;
  int bn = (b << 10) + n;
  const float4* ip = (const float4*)(in + (size_t)bn*64);
  const float4* wp = (const float4*)(Wm + (size_t)o*64);
  float s = bias[o];
  #pragma unroll
  for (int c = 0; c < 16; ++c){
    float4 a = ip[c], wv = wp[c];
    s = fmaf(a.x, wv.x, s); s = fmaf(a.y, wv.y, s);
    s = fmaf(a.z, wv.z, s); s = fmaf(a.w, wv.w, s);
  }
  outp[(size_t)bn*192 + o] = s;
}

// ------- flash-decode attention (no-max exp): 2 heads/block, b-affinity --------------
__global__ __launch_bounds__(256, 1) void k_attn_part(const float* __restrict__ qkv,
    float* __restrict__ pl, float* __restrict__ pacc){
  __shared__ __align__(16) float Ks[2][KPS*8];
  __shared__ __align__(16) float Vs[2][KPS*8];
  int blk = blockIdx.x;                // b(8, low bits) x ksl(8) x hp(4) = 256 blocks
  int b = blk & 7; int ksl = (blk >> 3) & 7; int hp = blk >> 6;
  int t = threadIdx.x;
  int hh = t >> 7;                     // wave-uniform head select within pair
  int h = hp*2 + hh;
  int lq = t & 127;
  for (int i = t; i < 2*KPS*8; i += 256){
    int hi = (i >= KPS*8) ? 1 : 0;
    int r = i - hi*KPS*8;
    int m = r >> 3, dd = r & 7;
    size_t base = ((size_t)b*ND + ksl*KPS + m)*192 + (hp*2 + hi)*8 + dd;
    Ks[hi][r] = qkv[base + 64];
    Vs[hi][r] = qkv[base + 128];
  }
  __syncthreads();
  const float scale = 0.35355339059327373f;
  float q[8][8];
  #pragma unroll
  for (int u = 0; u < 8; ++u){
    int n = u*128 + lq;
    const float4* qp = (const float4*)(qkv + ((size_t)b*ND + n)*192 + h*8);
    float4 q0 = qp[0], q1 = qp[1];
    q[u][0]=q0.x*scale; q[u][1]=q0.y*scale; q[u][2]=q0.z*scale; q[u][3]=q0.w*scale;
    q[u][4]=q1.x*scale; q[u][5]=q1.y*scale; q[u][6]=q1.z*scale; q[u][7]=q1.w*scale;
  }
  float l[8] = {};
  float acc[8][8] = {};
  for (int m = 0; m < KPS; ++m){
    float4 k0 = *(const float4*)&Ks[hh][m*8];
    float4 k1 = *(const float4*)&Ks[hh][m*8+4];
    float4 v0 = *(const float4*)&Vs[hh][m*8];
    float4 v1 = *(const float4*)&Vs[hh][m*8+4];
    #pragma unroll
    for (int u = 0; u < 8; ++u){
      float s;
      s = q[u][0]*k0.x;           s = fmaf(q[u][1], k0.y, s);
      s = fmaf(q[u][2], k0.z, s); s = fmaf(q[u][3], k0.w, s);
      s = fmaf(q[u][4], k1.x, s); s = fmaf(q[u][5], k1.y, s);
      s = fmaf(q[u][6], k1.z, s); s = fmaf(q[u][7], k1.w, s);
      float p = __expf(s);        // scores tiny: exp-without-max is safe; merge = sum
      l[u] += p;
      acc[u][0] = fmaf(p, v0.x, acc[u][0]);
      acc[u][1] = fmaf(p, v0.y, acc[u][1]);
      acc[u][2] = fmaf(p, v0.z, acc[u][2]);
      acc[u][3] = fmaf(p, v0.w, acc[u][3]);
      acc[u][4] = fmaf(p, v1.x, acc[u][4]);
      acc[u][5] = fmaf(p, v1.y, acc[u][5]);
      acc[u][6] = fmaf(p, v1.z, acc[u][6]);
      acc[u][7] = fmaf(p, v1.w, acc[u][7]);
    }
  }
  #pragma unroll
  for (int u = 0; u < 8; ++u){
    int n = u*128 + lq;
    size_t pidx = (((size_t)(b*8 + h))*8 + ksl)*ND + n;
    pl[pidx] = l[u];
    float4* ap = (float4*)&pacc[pidx*8];
    ap[0] = make_float4(acc[u][0], acc[u][1], acc[u][2], acc[u][3]);
    ap[1] = make_float4(acc[u][4], acc[u][5], acc[u][6], acc[u][7]);
  }
}

// ------- flash-decode combine: plain sums, b-affinity --------------------------------
__global__ __launch_bounds__(256) void k_attn_comb(const float* __restrict__ pl,
    const float* __restrict__ pacc, float* __restrict__ attno){
  int b = blockIdx.x & 7;
  int inner = (blockIdx.x >> 3)*256 + threadIdx.x;   // 0..8191 = h(8) x n(1024)
  int h = inner >> 10; int n = inner & 1023;
  int bh = b*8 + h;
  float L = 0.f;
  float o[8] = {};
  #pragma unroll
  for (int s = 0; s < KSL; ++s){
    size_t pidx = ((size_t)bh*8 + s)*ND + n;
    L += pl[pidx];
    const float4* ap = (const float4*)&pacc[pidx*8];
    float4 a0 = ap[0], a1 = ap[1];
    o[0] += a0.x; o[1] += a0.y; o[2] += a0.z; o[3] += a0.w;
    o[4] += a1.x; o[5] += a1.y; o[6] += a1.z; o[7] += a1.w;
  }
  float inv = 1.f/L;
  float4* dst = (float4*)&attno[((size_t)b*ND + n)*64 + h*8];
  dst[0] = make_float4(o[0]*inv, o[1]*inv, o[2]*inv, o[3]*inv);
  dst[1] = make_float4(o[4]*inv, o[5]*inv, o[6]*inv, o[7]*inv);
}

// ------- out-proj + pair-mean: emb[bn,f] = 0.5*(proj[2f]+proj[2f+1]), b-affinity -----
__global__ __launch_bounds__(256) void k_projmean(const float* __restrict__ attno,
    const float* __restrict__ Wo, const float* __restrict__ bo,
    float* __restrict__ emb){
  int b = blockIdx.x & 7;
  int inner = (blockIdx.x >> 3)*256 + threadIdx.x;   // 0..32767 = n(1024) x f(32)
  int n = inner >> 5; int f = inner & 31;
  int bn = (b << 10) + n;
  const float4* ip = (const float4*)(attno + (size_t)bn*64);
  int o0 = 2*f, o1 = 2*f + 1;
  const float4* w0 = (const float4*)(Wo + (size_t)o0*64);
  const float4* w1 = (const float4*)(Wo + (size_t)o1*64);
  float s0 = bo[o0], s1 = bo[o1];
  #pragma unroll
  for (int c = 0; c < 16; ++c){
    float4 a = ip[c], u = w0[c], v = w1[c];
    s0 = fmaf(a.x,u.x,s0); s0 = fmaf(a.y,u.y,s0); s0 = fmaf(a.z,u.z,s0); s0 = fmaf(a.w,u.w,s0);
    s1 = fmaf(a.x,v.x,s1); s1 = fmaf(a.y,v.y,s1); s1 = fmaf(a.z,v.z,s1); s1 = fmaf(a.w,v.w,s1);
  }
  emb[(size_t)bn*32 + f] = 0.5f*(s0 + s1);
}

// ---------------- fused attention pool: one block per b (block b -> XCD b) -----------
__global__ __launch_bounds__(256) void k_poolfuse(const float* __restrict__ emb,
    const float* __restrict__ attw, float* __restrict__ sout,
    float* __restrict__ pooled){
  __shared__ float part[8][32];
  __shared__ float meanv[32];
  __shared__ float gv[32];
  __shared__ float sc[ND];
  int b = blockIdx.x, t = threadIdx.x;
  int f = t & 31, j = t >> 5;
  const float* eb = emb + (size_t)b*ND*32;
  float s = 0.f;
  for (int n = j; n < ND; n += 8) s += eb[n*32 + f];
  part[j][f] = s;
  __syncthreads();
  if (t < 32){
    float m = 0.f;
    for (int j2 = 0; j2 < 8; ++j2) m += part[j2][t];
    meanv[t] = m * (1.f/ND);
  }
  __syncthreads();
  if (t < 32){
    float acc = 0.f;
    for (int f2 = 0; f2 < 32; ++f2) acc = fmaf(meanv[f2], attw[f2*32 + t], acc);
    gv[t] = tanhf(acc);
  }
  __syncthreads();
  for (int n = t; n < ND; n += 256){
    const float4* ep = (const float4*)(eb + n*32);
    float acc = 0.f;
    #pragma unroll
    for (int f4 = 0; f4 < 8; ++f4){
      float4 e = ep[f4];
      acc = fmaf(e.x, gv[f4*4+0], acc);
      acc = fmaf(e.y, gv[f4*4+1], acc);
      acc = fmaf(e.z, gv[f4*4+2], acc);
      acc = fmaf(e.w, gv[f4*4+3], acc);
    }
    float sg = 1.f/(1.f + __expf(-acc));
    sout[b*ND + n] = sg;
    sc[n] = sg;
  }
  __syncthreads();
  float pacc = 0.f;
  for (int n = j; n < ND; n += 8) pacc = fmaf(eb[n*32 + f], sc[n], pacc);
  part[j][f] = pacc;
  __syncthreads();
  if (t < 32){
    float m = 0.f;
    for (int j2 = 0; j2 < 8; ++j2) m += part[j2][t];
    pooled[b*32 + t] = m;
  }
}

// ---------------- NTN head: LDS-staged weights (2-phase, 32KB each) ----------------
__global__ __launch_bounds__(256) void k_head(const float* __restrict__ p1,
    const float* __restrict__ p2, const float* __restrict__ ntnw,
    const float* __restrict__ ntnv, const float* __restrict__ ntnb,
    const float* __restrict__ fc1w, const float* __restrict__ fc1b,
    const float* __restrict__ scw, const float* __restrict__ scb,
    float* __restrict__ outscore){
  __shared__ __align__(16) float Wl[8192];
  __shared__ float Vl[512];
  __shared__ float F1[256];
  __shared__ float ds[8][32];
  __shared__ float tv[8][16];
  __shared__ float hv[8][16];
  int t = threadIdx.x;
  {
    int b = t >> 5, f = t & 31;
    ds[b][f] = p1[b*32+f] - p2[b*32+f];
  }
  for (int i = t; i < 512; i += 256) Vl[i] = ntnv[i];
  if (t < 256) F1[t] = fc1w[t];
  float acc = 0.f;
  for (int ph = 0; ph < 2; ++ph){
    __syncthreads();
    {
      const float4* src = (const float4*)(ntnw + ph*8192);
      float4* dst = (float4*)Wl;
      for (int i = t; i < 2048; i += 256) dst[i] = src[i];
    }
    __syncthreads();
    if (t < 128){
      int b = t >> 4, tt = t & 15;
      for (int fi = 0; fi < 16; ++fi){
        float df = ds[b][ph*16 + fi];
        #pragma unroll 8
        for (int gg = 0; gg < 32; ++gg)
          acc = fmaf(df*ds[b][gg], Wl[(fi*32+gg)*16 + tt], acc);
      }
    }
  }
  if (t < 128){
    int b = t >> 4, tt = t & 15;
    acc += ntnb[tt];
    for (int gg = 0; gg < 32; ++gg) acc = fmaf(ds[b][gg], Vl[tt*32+gg], acc);
    tv[b][tt] = fmaxf(acc, 0.f);
  }
  __syncthreads();
  if (t < 128){
    int b = t >> 4, i = t & 15;
    float a2 = fc1b[i];
    for (int kk = 0; kk < 16; ++kk) a2 = fmaf(tv[b][kk], F1[i*16+kk], a2);
    hv[b][i] = fmaxf(a2, 0.f);
  }
  __syncthreads();
  if (t < 8){
    float a3 = scb[0];
    for (int i = 0; i < 16; ++i) a3 = fmaf(hv[t][i], scw[i], a3);
    outscore[t] = 1.f/(1.f + __expf(-a3));
  }
}

// =====================================================================================
extern "C" void kernel_launch(void* const* d_in, const int* in_sizes, int n_in,
                              void* d_out, int out_size, void* d_ws, size_t ws_size,
                              hipStream_t stream) {
  auto F = [&](int i){ return (const float*)d_in[i]; };
  const float* feats[2] = { F(0), F(1) };
  const float* cw[3] = { F(2), F(6), F(10) };
  const float* cb[3] = { F(3), F(7), F(11) };
  const float* cg[3] = { F(4), F(8), F(12) };
  const float* cB[3] = { F(5), F(9), F(13) };
  const float* sw[3] = { F(14), F(18), F(22) };
  const float* sb[3] = { F(15), F(19), F(23) };
  const float* sg[3] = { F(16), F(20), F(24) };
  const float* sB[3] = { F(17), F(21), F(25) };
  const float* mha_wi = F(26); const float* mha_bi = F(27);
  const float* mha_wo = F(28); const float* mha_bo = F(29);
  const float* att_w  = F(30);
  const float* ntn_w  = F(31); const float* ntn_v = F(32); const float* ntn_b = F(33);
  const float* fc1_w  = F(34); const float* fc1_b = F(35);
  const float* sc_w   = F(36); const float* sc_b  = F(37);
  float* out = (float*)d_out;

  char* ws = (char*)d_ws;
  // MHA scratch in the low region (formerly negdist; knn no longer writes it)
  float* qkv   = (float*)ws;                              // [0, 6 MiB)
  float* attno = (float*)(ws + ((size_t)8  << 20));       // [8, 10 MiB)
  float* plb   = (float*)(ws + ((size_t)10 << 20));       // [10, 12 MiB)
  float* paccb = (float*)(ws + ((size_t)14 << 20));       // [14, 30 MiB)
  size_t off = 33554432;
  float* xA   = (float*)(ws + off); off += 4194304;
  float* xB   = (float*)(ws + off); off += 4194304;
  float* zs   = (float*)(ws + off); off += 4194304;
  float* cvb  = (float*)(ws + off); off += 4194304;
  int*   idxb = (int*)  (ws + off); off += 655360;
  float* xxb  = (float*)(ws + off); off += 32768;
  float* fuse = (float*)(ws + off); off += 2097152;
  float* emb1 = (float*)(ws + off); off += 1048576;
  float* emb2 = (float*)(ws + off); off += 1048576;
  float* pool1= (float*)(ws + off); off += 4096;
  float* pool2= (float*)(ws + off); off += 4096;

  auto knn = [&](const float* xin, int CS, int nch8){
    k_knn<<<512, 256, 0, stream>>>(xin, xxb, idxb, CS, nch8);
  };
  auto phA = [&](const float* xin, int C, int XS, int O, const float* W, const float* bb,
                 const float* gg, const float* be){
    if (O == 64)       k_phaseA<64> <<<BD*ND/32, 256, 0, stream>>>(xin, W, bb, gg, be, zs, cvb, C, XS);
    else if (O == 128) k_phaseA<128><<<BD*ND/32, 256, 0, stream>>>(xin, W, bb, gg, be, zs, cvb, C, XS);
    else               k_phaseA<32> <<<BD*ND/32, 256, 0, stream>>>(xin, W, bb, gg, be, zs, cvb, C, XS);
  };

  for (int br = 0; br < 2; ++br){
    const float* feat = feats[br];
    float* emb    = br ? emb2  : emb1;
    float* sout   = out + 8 + br*(BD*ND);
    float* pooled = br ? pool2 : pool1;
    for (int part = 0; part < 2; ++part){
      const float* const* Wl = part ? sw : cw;
      const float* const* bl = part ? sb : cb;
      const float* const* gl = part ? sg : cg;
      const float* const* Bl = part ? sB : cB;
      int C0 = part ? 12 : 3;
      int CS0 = part ? 12 : 4;
      // layer 0: C0 -> 64
      if (part) k_prep<12,12><<<BD*ND/256, 256, 0, stream>>>(feat, xA, xxb, 3);
      else      k_prep<3, 4> <<<BD*ND/256, 256, 0, stream>>>(feat, xA, xxb, 0);
      knn(xA, CS0, part ? 2 : 1);
      phA(xA, C0, CS0, 64, Wl[0], bl[0], gl[0], Bl[0]);
      k_phaseB<true,true><<<BD*ND/4, 256, 0, stream>>>(zs, cvb, idxb, xB, xxb, 64, 0, 0);
      // layer 1: 64 -> 128 (xx produced by phaseB)
      knn(xB, 64, 8);
      phA(xB, 64, 64, 128, Wl[1], bl[1], gl[1], Bl[1]);
      k_phaseB<true,true><<<BD*ND/4, 256, 0, stream>>>(zs, cvb, idxb, xA, xxb, 128, 0, 0);
      // layer 2: 128 -> 32, written into fuse at column offset (row-major)
      knn(xA, 128, 16);
      phA(xA, 128, 128, 32, Wl[2], bl[2], gl[2], Bl[2]);
      k_phaseB<false,false><<<BD*ND/4, 256, 0, stream>>>(zs, cvb, idxb, fuse, nullptr, 32, 64, part*32);
    }
    // MHA (flash-decode, no-max exp)
    k_lin<<<(BD*ND*192)/256, 256, 0, stream>>>(fuse, mha_wi, mha_bi, qkv);
    k_attn_part<<<BD*4*KSL, 256, 0, stream>>>(qkv, plb, paccb);
    k_attn_comb<<<(BD*8*ND)/256, 256, 0, stream>>>(plb, paccb, attno);
    k_projmean<<<(BD*ND*32)/256, 256, 0, stream>>>(attno, mha_wo, mha_bo, emb);
    // fused attention pool
    k_poolfuse<<<BD, 256, 0, stream>>>(emb, att_w, sout, pooled);
  }
  k_head<<<1, 256, 0, stream>>>(pool1, pool2, ntn_w, ntn_v, ntn_b,
                                fc1_w, fc1_b, sc_w, sc_b, out);
}

// Round 9
// 1381.748 us; speedup vs baseline: 1.5080x; 1.5080x over previous
//
#include <hip/hip_runtime.h>
#include <math.h>

#define BD 8
#define ND 1024
#define KNN 20
#define NEGS 0.2f
#define BNSC 0.99999500003749969482f
#define KSL 8      // key slices for flash-decode attention
#define KPS 128    // keys per slice

__device__ __forceinline__ float leakyf(float y){ return y >= 0.f ? y : NEGS*y; }

// x buffers (xA/xB) use the knn-tiled layout: x_t[b][g][n][4], g = feature quad.
// ALL per-batch kernels map b = blockIdx.x & 7: batch-per-XCD L2 affinity (r7:
// FETCH 16.7->2.2 MB). knn stages via LDS (r8 lesson: LDS broadcast-amplifies --
// direct L2 reads made every wave pull the full tile itself, 184us). Chunk = 16
// cols staged at once, inner loop runs twice (8 cols each, same regs as r7) ->
// barrier count halves while register pressure stays at r7's proven 72.
__global__ __launch_bounds__(256) void k_prep_dummy(){}

// -------- fused input slice + transpose + xx: tiled write, b-affinity ----------------
template<int C, int CS>
__global__ __launch_bounds__(256) void k_prep(const float* __restrict__ feat,
                                              float* __restrict__ x,
                                              float* __restrict__ xx, int c0){
  int b = blockIdx.x & 7;
  int n = (blockIdx.x >> 3)*256 + threadIdx.x;
  float v[CS];
  float s = 0.f;
  #pragma unroll
  for (int c = 0; c < C; ++c){
    v[c] = feat[((size_t)(b*15) + c0 + c)*ND + n];
    s = fmaf(v[c], v[c], s);
  }
  #pragma unroll
  for (int c = C; c < CS; ++c) v[c] = 0.f;
  #pragma unroll
  for (int g = 0; g < CS/4; ++g)
    *(float4*)&x[(size_t)(b*CS + g*4)*ND + (size_t)n*4] =
        make_float4(v[g*4], v[g*4+1], v[g*4+2], v[g*4+3]);
  xx[b*ND + n] = s;
}

// -------- fused gram + exact top-20: 16-col staged chunks, 2-pass inner loop ---------
// block = 16 rows (4 waves x 4 rows); 4 quad-arrays staged per chunk (64 KB, still
// 2 blocks/CU). Inner loop = r7's proven 8-col pass, run twice -> same live-register
// set (rv 8xfloat4), half the barrier pairs. FMA order per (row,col) stays strictly
// ascending c -> bitwise-identical. nchunk = ceil(CS/16).
__global__ __launch_bounds__(256)
void k_knn(const float* __restrict__ x,
    const float* __restrict__ xx, int* __restrict__ idxp, int CS, int nchunk){
  __shared__ __align__(16) float Xc[4][4096];   // 64 KB: 4 feature-quad arrays
  int b = blockIdx.x & 7;
  int r0 = (blockIdx.x >> 3)*16;
  int t = threadIdx.x;
  int lane = t & 63;
  int w = __builtin_amdgcn_readfirstlane(t >> 6);   // wave-uniform wave id
  const float* xb = x + (size_t)b*ND*CS;            // tiled [G][n][4]
  float acc[4][16];
  #pragma unroll
  for (int j = 0; j < 4; ++j)
    #pragma unroll
    for (int q = 0; q < 16; ++q) acc[j][q] = 0.f;
  for (int ch = 0; ch < nchunk; ++ch){
    int gb = 4*ch;                      // first quad of this chunk
    __syncthreads();
    for (int m = t; m < 1024; m += 256){
      #pragma unroll
      for (int g = 0; g < 4; ++g){
        // contiguous 16B/lane from tiled x; zero-fill padded quads
        *(float4*)&Xc[g][m*4] = ((gb + g)*4 < CS)
            ? *(const float4*)&xb[((size_t)(gb + g)*ND + m)*4]
            : make_float4(0.f,0.f,0.f,0.f);
      }
    }
    __syncthreads();
    #pragma unroll
    for (int p = 0; p < 2; ++p){        // two 8-col passes: quads (2p, 2p+1)
      // row fragments from LDS (rows are columns; uniform-addr broadcast)
      float4 rv0[4], rv1[4];
      #pragma unroll
      for (int j = 0; j < 4; ++j){
        rv0[j] = *(const float4*)&Xc[2*p  ][(r0 + w*4 + j)*4];
        rv1[j] = *(const float4*)&Xc[2*p+1][(r0 + w*4 + j)*4];
      }
      #pragma unroll
      for (int q = 0; q < 16; ++q){
        float4 cv0 = *(const float4*)&Xc[2*p  ][(q*64 + lane)*4];
        float4 cv1 = *(const float4*)&Xc[2*p+1][(q*64 + lane)*4];
        #pragma unroll
        for (int j = 0; j < 4; ++j){
          float s = acc[j][q];   // ascending col order: bitwise-stable result
          s = fmaf(rv0[j].x, cv0.x, s); s = fmaf(rv0[j].y, cv0.y, s);
          s = fmaf(rv0[j].z, cv0.z, s); s = fmaf(rv0[j].w, cv0.w, s);
          s = fmaf(rv1[j].x, cv1.x, s); s = fmaf(rv1[j].y, cv1.y, s);
          s = fmaf(rv1[j].z, cv1.z, s); s = fmaf(rv1[j].w, cv1.w, s);
          acc[j][q] = s;
        }
      }
    }
  }
  // transform to negdist = 2*dot - xx_r - xx_m, then to sortable uints
  float xxm[16];
  #pragma unroll
  for (int q = 0; q < 16; ++q) xxm[q] = xx[b*ND + q*64 + lane];
  unsigned uk[4][16];
  #pragma unroll
  for (int j = 0; j < 4; ++j){
    float xr = xx[b*ND + r0 + w*4 + j];
    #pragma unroll
    for (int q = 0; q < 16; ++q){
      float f = 2.f*acc[j][q] - xr - xxm[q];
      unsigned bv = __float_as_uint(f);
      uk[j][q] = (bv & 0x80000000u) ? ~bv : (bv | 0x80000000u);  // order-preserving
    }
  }
  // radix binary search for T = 20th-largest key per row (bit 31: only the diagonal
  // reaches it, count==1<20 always -> skip). Early exit at exact count==20 (set-equal).
  unsigned pref[4] = {0u, 0u, 0u, 0u};
  unsigned done = 0u;
  #pragma unroll 1
  for (int bit = 30; bit >= 0; --bit){
    #pragma unroll
    for (int u = 0; u < 4; ++u){
      if (done & (1u << u)) continue;           // wave-uniform (ballot-derived)
      unsigned cand = pref[u] | (1u << bit);
      int c = 0;
      #pragma unroll
      for (int q = 0; q < 16; ++q)
        c += (int)__popcll(__ballot(uk[u][q] >= cand));
      if (c >= KNN){
        pref[u] = cand;
        if (c == KNN) done |= (1u << u);
      }
    }
    if (done == 15u) break;
  }
  // emit: all keys > T, plus lowest-global-index keys == T to fill to 20
  unsigned long long mlt = (1ull << lane) - 1ull;   // lanes below me
  #pragma unroll
  for (int u = 0; u < 4; ++u){
    unsigned T = pref[u];
    int cg = 0;
    #pragma unroll
    for (int q = 0; q < 16; ++q) cg += (int)__popcll(__ballot(uk[u][q] > T));
    int need_eq = KNN - cg;                          // >= 1 by construction
    int* op = &idxp[((size_t)(b*ND + r0 + w*4 + u))*KNN];
    int run_gt = 0, run_eq = 0;
    #pragma unroll
    for (int q = 0; q < 16; ++q){
      unsigned k = uk[u][q];
      unsigned long long bg = __ballot(k > T);
      unsigned long long be = __ballot(k == T);
      if (k > T) op[run_gt + (int)__popcll(bg & mlt)] = q*64 + lane;
      if (k == T){
        int r = run_eq + (int)__popcll(be & mlt);
        if (r < need_eq) op[cg + r] = q*64 + lane;
      }
      run_gt += (int)__popcll(bg);
      run_eq += (int)__popcll(be);
    }
  }
}

// ------ phase A (register-blocked), x read from tiled layout, b-affinity -------------
template<int O>
__global__ __launch_bounds__(256) void k_phaseA(const float* __restrict__ x,
    const float* __restrict__ W, const float* __restrict__ bias,
    const float* __restrict__ gamma, const float* __restrict__ beta,
    float* __restrict__ zs, float* __restrict__ ccv, int C, int XS){
  constexpr int TO = O/16;
  constexpr int WP = O + 4;
  __shared__ float W1s[32*WP];
  __shared__ float dWs[32*WP];
  __shared__ float Xs[32*33];
  int blk = blockIdx.x;
  int b = blk & 7, n0 = (blk >> 3)*32;
  int t = threadIdx.x;
  int ot = t & 15, nt = t >> 4;
  int obase = ot*TO;
  int nl = nt*2;
  float az[TO][2] = {}, ac[TO][2] = {};
  for (int cc = 0; cc < C; cc += 32){
    int KC = (C - cc < 32) ? (C - cc) : 32;
    int NG = (KC + 3) >> 2;
    for (int i = t; i < O*KC; i += 256){
      int o = i % O, c = i / O;
      float w1 = W[(size_t)o*2*C + cc + c];
      float w2 = W[(size_t)o*2*C + C + cc + c];
      W1s[c*WP + o] = w1;
      dWs[c*WP + o] = w2 - w1;
    }
    for (int i = t; i < 32*NG; i += 256){
      int row = i & 31, g = i >> 5;
      float4 v = *(const float4*)&x[(size_t)(b*XS + cc + g*4)*ND + (size_t)(n0+row)*4];
      Xs[(g*4+0)*33 + row] = v.x;
      Xs[(g*4+1)*33 + row] = v.y;
      Xs[(g*4+2)*33 + row] = v.z;
      Xs[(g*4+3)*33 + row] = v.w;
    }
    __syncthreads();
    for (int c = 0; c < KC; ++c){
      float xv0 = Xs[c*33 + nl];
      float xv1 = Xs[c*33 + nl + 1];
      #pragma unroll
      for (int i = 0; i < TO; ++i){
        float w1 = W1s[c*WP + obase + i];
        float dw = dWs[c*WP + obase + i];
        az[i][0] = fmaf(w1, xv0, az[i][0]);
        az[i][1] = fmaf(w1, xv1, az[i][1]);
        ac[i][0] = fmaf(dw, xv0, ac[i][0]);
        ac[i][1] = fmaf(dw, xv1, ac[i][1]);
      }
    }
    __syncthreads();
  }
  #pragma unroll
  for (int i = 0; i < TO; ++i){
    int o = obase + i;
    float alpha = gamma[o]*BNSC;
    float bb = bias[o], be = beta[o];
    #pragma unroll
    for (int q = 0; q < 2; ++q){
      int n = n0 + nl + q;
      size_t off = ((size_t)b*ND + n)*O + o;
      zs[off]  = az[i][q]*alpha;
      ccv[off] = fmaf(ac[i][q] + bb, alpha, be);
    }
  }
}

// ------ phase B: out = max_k leaky(zs[idx_k]+cc); TILED knn-layout writes; b-affinity -
template<bool DOXX, bool TILED>
__global__ __launch_bounds__(256) void k_phaseB(const float* __restrict__ zs,
    const float* __restrict__ ccv, const int* __restrict__ idxp,
    float* __restrict__ outp, float* __restrict__ xxout,
    int O, int ostride, int ooff){
  int t = threadIdx.x;
  int lane = t & 63, w = t >> 6;
  int b = blockIdx.x & 7;
  int n = (blockIdx.x >> 3)*4 + w;
  int gn = (b << 10) + n;
  int mm[KNN];
  const int* ip = idxp + (size_t)gn*KNN;
  #pragma unroll
  for (int k = 0; k < KNN; ++k) mm[k] = ip[k];
  float sq = 0.f;
  for (int o = lane; o < O; o += 64){
    float cvv = ccv[(size_t)gn*O + o];
    float mx = -INFINITY;
    #pragma unroll 4
    for (int k = 0; k < KNN; ++k){
      float v = leakyf(zs[((size_t)(b*ND) + mm[k])*O + o] + cvv);
      mx = fmaxf(mx, v);
    }
    if (TILED)
      outp[(size_t)(b*O + (o & ~3))*ND + (size_t)n*4 + (o & 3)] = mx;
    else
      outp[(size_t)gn*ostride + ooff + o] = mx;
    if (DOXX) sq = fmaf(mx, mx, sq);
  }
  if (DOXX){
    #pragma unroll
    for (int off = 32; off; off >>= 1) sq += __shfl_down(sq, off);
    if (lane == 0) xxout[gn] = sq;
  }
}

// --------- qkv[bn,o] = fuse[bn,:].Wi[o,:] + bi[o]  (raw Wi, float4), b-affinity ------
__global__ __launch_bounds__(256) void k_lin(const float* __restrict__ in,
    const float* __restrict__ Wm, const float* __restrict__ bias,
    float* __restrict__ outp){
  int b = blockIdx.x & 7;
  int inner = (blockIdx.x >> 3)*256 + threadIdx.x;   // 0..196607
  int o = inner % 192; int n = inner / 192;
  int bn = (b << 10) + n;
  const float4* ip = (const float4*)(in + (size_t)bn*64);
  const float4* wp = (const float4*)(Wm + (size_t)o*64);
  float s = bias[o];
  #pragma unroll
  for (int c = 0; c < 16; ++c){
    float4 a = ip[c], wv = wp[c];
    s = fmaf(a.x, wv.x, s); s = fmaf(a.y, wv.y, s);
    s = fmaf(a.z, wv.z, s); s = fmaf(a.w, wv.w, s);
  }
  outp[(size_t)bn*192 + o] = s;
}

// ------- flash-decode attention (no-max exp): 2 heads/block, b-affinity --------------
__global__ __launch_bounds__(256, 1) void k_attn_part(const float* __restrict__ qkv,
    float* __restrict__ pl, float* __restrict__ pacc){
  __shared__ __align__(16) float Ks[2][KPS*8];
  __shared__ __align__(16) float Vs[2][KPS*8];
  int blk = blockIdx.x;                // b(8, low bits) x ksl(8) x hp(4) = 256 blocks
  int b = blk & 7; int ksl = (blk >> 3) & 7; int hp = blk >> 6;
  int t = threadIdx.x;
  int hh = t >> 7;                     // wave-uniform head select within pair
  int h = hp*2 + hh;
  int lq = t & 127;
  for (int i = t; i < 2*KPS*8; i += 256){
    int hi = (i >= KPS*8) ? 1 : 0;
    int r = i - hi*KPS*8;
    int m = r >> 3, dd = r & 7;
    size_t base = ((size_t)b*ND + ksl*KPS + m)*192 + (hp*2 + hi)*8 + dd;
    Ks[hi][r] = qkv[base + 64];
    Vs[hi][r] = qkv[base + 128];
  }
  __syncthreads();
  const float scale = 0.35355339059327373f;
  float q[8][8];
  #pragma unroll
  for (int u = 0; u < 8; ++u){
    int n = u*128 + lq;
    const float4* qp = (const float4*)(qkv + ((size_t)b*ND + n)*192 + h*8);
    float4 q0 = qp[0], q1 = qp[1];
    q[u][0]=q0.x*scale; q[u][1]=q0.y*scale; q[u][2]=q0.z*scale; q[u][3]=q0.w*scale;
    q[u][4]=q1.x*scale; q[u][5]=q1.y*scale; q[u][6]=q1.z*scale; q[u][7]=q1.w*scale;
  }
  float l[8] = {};
  float acc[8][8] = {};
  for (int m = 0; m < KPS; ++m){
    float4 k0 = *(const float4*)&Ks[hh][m*8];
    float4 k1 = *(const float4*)&Ks[hh][m*8+4];
    float4 v0 = *(const float4*)&Vs[hh][m*8];
    float4 v1 = *(const float4*)&Vs[hh][m*8+4];
    #pragma unroll
    for (int u = 0; u < 8; ++u){
      float s;
      s = q[u][0]*k0.x;           s = fmaf(q[u][1], k0.y, s);
      s = fmaf(q[u][2], k0.z, s); s = fmaf(q[u][3], k0.w, s);
      s = fmaf(q[u][4], k1.x, s); s = fmaf(q[u][5], k1.y, s);
      s = fmaf(q[u][6], k1.z, s); s = fmaf(q[u][7], k1.w, s);
      float p = __expf(s);        // scores tiny: exp-without-max is safe; merge = sum
      l[u] += p;
      acc[u][0] = fmaf(p, v0.x, acc[u][0]);
      acc[u][1] = fmaf(p, v0.y, acc[u][1]);
      acc[u][2] = fmaf(p, v0.z, acc[u][2]);
      acc[u][3] = fmaf(p, v0.w, acc[u][3]);
      acc[u][4] = fmaf(p, v1.x, acc[u][4]);
      acc[u][5] = fmaf(p, v1.y, acc[u][5]);
      acc[u][6] = fmaf(p, v1.z, acc[u][6]);
      acc[u][7] = fmaf(p, v1.w, acc[u][7]);
    }
  }
  #pragma unroll
  for (int u = 0; u < 8; ++u){
    int n = u*128 + lq;
    size_t pidx = (((size_t)(b*8 + h))*8 + ksl)*ND + n;
    pl[pidx] = l[u];
    float4* ap = (float4*)&pacc[pidx*8];
    ap[0] = make_float4(acc[u][0], acc[u][1], acc[u][2], acc[u][3]);
    ap[1] = make_float4(acc[u][4], acc[u][5], acc[u][6], acc[u][7]);
  }
}

// ------- flash-decode combine: plain sums, b-affinity --------------------------------
__global__ __launch_bounds__(256) void k_attn_comb(const float* __restrict__ pl,
    const float* __restrict__ pacc, float* __restrict__ attno){
  int b = blockIdx.x & 7;
  int inner = (blockIdx.x >> 3)*256 + threadIdx.x;   // 0..8191 = h(8) x n(1024)
  int h = inner >> 10; int n = inner & 1023;
  int bh = b*8 + h;
  float L = 0.f;
  float o[8] = {};
  #pragma unroll
  for (int s = 0; s < KSL; ++s){
    size_t pidx = ((size_t)bh*8 + s)*ND + n;
    L += pl[pidx];
    const float4* ap = (const float4*)&pacc[pidx*8];
    float4 a0 = ap[0], a1 = ap[1];
    o[0] += a0.x; o[1] += a0.y; o[2] += a0.z; o[3] += a0.w;
    o[4] += a1.x; o[5] += a1.y; o[6] += a1.z; o[7] += a1.w;
  }
  float inv = 1.f/L;
  float4* dst = (float4*)&attno[((size_t)b*ND + n)*64 + h*8];
  dst[0] = make_float4(o[0]*inv, o[1]*inv, o[2]*inv, o[3]*inv);
  dst[1] = make_float4(o[4]*inv, o[5]*inv, o[6]*inv, o[7]*inv);
}

// ------- out-proj + pair-mean: emb[bn,f] = 0.5*(proj[2f]+proj[2f+1]), b-affinity -----
__global__ __launch_bounds__(256) void k_projmean(const float* __restrict__ attno,
    const float* __restrict__ Wo, const float* __restrict__ bo,
    float* __restrict__ emb){
  int b = blockIdx.x & 7;
  int inner = (blockIdx.x >> 3)*256 + threadIdx.x;   // 0..32767 = n(1024) x f(32)
  int n = inner >> 5; int f = inner & 31;
  int bn = (b << 10) + n;
  const float4* ip = (const float4*)(attno + (size_t)bn*64);
  int o0 = 2*f, o1 = 2*f + 1;
  const float4* w0 = (const float4*)(Wo + (size_t)o0*64);
  const float4* w1 = (const float4*)(Wo + (size_t)o1*64);
  float s0 = bo[o0], s1 = bo[o1];
  #pragma unroll
  for (int c = 0; c < 16; ++c){
    float4 a = ip[c], u = w0[c], v = w1[c];
    s0 = fmaf(a.x,u.x,s0); s0 = fmaf(a.y,u.y,s0); s0 = fmaf(a.z,u.z,s0); s0 = fmaf(a.w,u.w,s0);
    s1 = fmaf(a.x,v.x,s1); s1 = fmaf(a.y,v.y,s1); s1 = fmaf(a.z,v.z,s1); s1 = fmaf(a.w,v.w,s1);
  }
  emb[(size_t)bn*32 + f] = 0.5f*(s0 + s1);
}

// ---------------- fused attention pool: one block per b (block b -> XCD b) -----------
__global__ __launch_bounds__(256) void k_poolfuse(const float* __restrict__ emb,
    const float* __restrict__ attw, float* __restrict__ sout,
    float* __restrict__ pooled){
  __shared__ float part[8][32];
  __shared__ float meanv[32];
  __shared__ float gv[32];
  __shared__ float sc[ND];
  int b = blockIdx.x, t = threadIdx.x;
  int f = t & 31, j = t >> 5;
  const float* eb = emb + (size_t)b*ND*32;
  float s = 0.f;
  for (int n = j; n < ND; n += 8) s += eb[n*32 + f];
  part[j][f] = s;
  __syncthreads();
  if (t < 32){
    float m = 0.f;
    for (int j2 = 0; j2 < 8; ++j2) m += part[j2][t];
    meanv[t] = m * (1.f/ND);
  }
  __syncthreads();
  if (t < 32){
    float acc = 0.f;
    for (int f2 = 0; f2 < 32; ++f2) acc = fmaf(meanv[f2], attw[f2*32 + t], acc);
    gv[t] = tanhf(acc);
  }
  __syncthreads();
  for (int n = t; n < ND; n += 256){
    const float4* ep = (const float4*)(eb + n*32);
    float acc = 0.f;
    #pragma unroll
    for (int f4 = 0; f4 < 8; ++f4){
      float4 e = ep[f4];
      acc = fmaf(e.x, gv[f4*4+0], acc);
      acc = fmaf(e.y, gv[f4*4+1], acc);
      acc = fmaf(e.z, gv[f4*4+2], acc);
      acc = fmaf(e.w, gv[f4*4+3], acc);
    }
    float sg = 1.f/(1.f + __expf(-acc));
    sout[b*ND + n] = sg;
    sc[n] = sg;
  }
  __syncthreads();
  float pacc = 0.f;
  for (int n = j; n < ND; n += 8) pacc = fmaf(eb[n*32 + f], sc[n], pacc);
  part[j][f] = pacc;
  __syncthreads();
  if (t < 32){
    float m = 0.f;
    for (int j2 = 0; j2 < 8; ++j2) m += part[j2][t];
    pooled[b*32 + t] = m;
  }
}

// ---------------- NTN head: LDS-staged weights (2-phase, 32KB each) ----------------
__global__ __launch_bounds__(256) void k_head(const float* __restrict__ p1,
    const float* __restrict__ p2, const float* __restrict__ ntnw,
    const float* __restrict__ ntnv, const float* __restrict__ ntnb,
    const float* __restrict__ fc1w, const float* __restrict__ fc1b,
    const float* __restrict__ scw, const float* __restrict__ scb,
    float* __restrict__ outscore){
  __shared__ __align__(16) float Wl[8192];
  __shared__ float Vl[512];
  __shared__ float F1[256];
  __shared__ float ds[8][32];
  __shared__ float tv[8][16];
  __shared__ float hv[8][16];
  int t = threadIdx.x;
  {
    int b = t >> 5, f = t & 31;
    ds[b][f] = p1[b*32+f] - p2[b*32+f];
  }
  for (int i = t; i < 512; i += 256) Vl[i] = ntnv[i];
  if (t < 256) F1[t] = fc1w[t];
  float acc = 0.f;
  for (int ph = 0; ph < 2; ++ph){
    __syncthreads();
    {
      const float4* src = (const float4*)(ntnw + ph*8192);
      float4* dst = (float4*)Wl;
      for (int i = t; i < 2048; i += 256) dst[i] = src[i];
    }
    __syncthreads();
    if (t < 128){
      int b = t >> 4, tt = t & 15;
      for (int fi = 0; fi < 16; ++fi){
        float df = ds[b][ph*16 + fi];
        #pragma unroll 8
        for (int gg = 0; gg < 32; ++gg)
          acc = fmaf(df*ds[b][gg], Wl[(fi*32+gg)*16 + tt], acc);
      }
    }
  }
  if (t < 128){
    int b = t >> 4, tt = t & 15;
    acc += ntnb[tt];
    for (int gg = 0; gg < 32; ++gg) acc = fmaf(ds[b][gg], Vl[tt*32+gg], acc);
    tv[b][tt] = fmaxf(acc, 0.f);
  }
  __syncthreads();
  if (t < 128){
    int b = t >> 4, i = t & 15;
    float a2 = fc1b[i];
    for (int kk = 0; kk < 16; ++kk) a2 = fmaf(tv[b][kk], F1[i*16+kk], a2);
    hv[b][i] = fmaxf(a2, 0.f);
  }
  __syncthreads();
  if (t < 8){
    float a3 = scb[0];
    for (int i = 0; i < 16; ++i) a3 = fmaf(hv[t][i], scw[i], a3);
    outscore[t] = 1.f/(1.f + __expf(-a3));
  }
}

// =====================================================================================
extern "C" void kernel_launch(void* const* d_in, const int* in_sizes, int n_in,
                              void* d_out, int out_size, void* d_ws, size_t ws_size,
                              hipStream_t stream) {
  auto F = [&](int i){ return (const float*)d_in[i]; };
  const float* feats[2] = { F(0), F(1) };
  const float* cw[3] = { F(2), F(6), F(10) };
  const float* cb[3] = { F(3), F(7), F(11) };
  const float* cg[3] = { F(4), F(8), F(12) };
  const float* cB[3] = { F(5), F(9), F(13) };
  const float* sw[3] = { F(14), F(18), F(22) };
  const float* sb[3] = { F(15), F(19), F(23) };
  const float* sg[3] = { F(16), F(20), F(24) };
  const float* sB[3] = { F(17), F(21), F(25) };
  const float* mha_wi = F(26); const float* mha_bi = F(27);
  const float* mha_wo = F(28); const float* mha_bo = F(29);
  const float* att_w  = F(30);
  const float* ntn_w  = F(31); const float* ntn_v = F(32); const float* ntn_b = F(33);
  const float* fc1_w  = F(34); const float* fc1_b = F(35);
  const float* sc_w   = F(36); const float* sc_b  = F(37);
  float* out = (float*)d_out;

  char* ws = (char*)d_ws;
  // MHA scratch in the low region (formerly negdist; knn no longer writes it)
  float* qkv   = (float*)ws;                              // [0, 6 MiB)
  float* attno = (float*)(ws + ((size_t)8  << 20));       // [8, 10 MiB)
  float* plb   = (float*)(ws + ((size_t)10 << 20));       // [10, 12 MiB)
  float* paccb = (float*)(ws + ((size_t)14 << 20));       // [14, 30 MiB)
  size_t off = 33554432;
  float* xA   = (float*)(ws + off); off += 4194304;
  float* xB   = (float*)(ws + off); off += 4194304;
  float* zs   = (float*)(ws + off); off += 4194304;
  float* cvb  = (float*)(ws + off); off += 4194304;
  int*   idxb = (int*)  (ws + off); off += 655360;
  float* xxb  = (float*)(ws + off); off += 32768;
  float* fuse = (float*)(ws + off); off += 2097152;
  float* emb1 = (float*)(ws + off); off += 1048576;
  float* emb2 = (float*)(ws + off); off += 1048576;
  float* pool1= (float*)(ws + off); off += 4096;
  float* pool2= (float*)(ws + off); off += 4096;

  auto knn = [&](const float* xin, int CS, int nch16){
    k_knn<<<512, 256, 0, stream>>>(xin, xxb, idxb, CS, nch16);
  };
  auto phA = [&](const float* xin, int C, int XS, int O, const float* W, const float* bb,
                 const float* gg, const float* be){
    if (O == 64)       k_phaseA<64> <<<BD*ND/32, 256, 0, stream>>>(xin, W, bb, gg, be, zs, cvb, C, XS);
    else if (O == 128) k_phaseA<128><<<BD*ND/32, 256, 0, stream>>>(xin, W, bb, gg, be, zs, cvb, C, XS);
    else               k_phaseA<32> <<<BD*ND/32, 256, 0, stream>>>(xin, W, bb, gg, be, zs, cvb, C, XS);
  };

  for (int br = 0; br < 2; ++br){
    const float* feat = feats[br];
    float* emb    = br ? emb2  : emb1;
    float* sout   = out + 8 + br*(BD*ND);
    float* pooled = br ? pool2 : pool1;
    for (int part = 0; part < 2; ++part){
      const float* const* Wl = part ? sw : cw;
      const float* const* bl = part ? sb : cb;
      const float* const* gl = part ? sg : cg;
      const float* const* Bl = part ? sB : cB;
      int C0 = part ? 12 : 3;
      int CS0 = part ? 12 : 4;
      // layer 0: C0 -> 64 (single 16-col chunk)
      if (part) k_prep<12,12><<<BD*ND/256, 256, 0, stream>>>(feat, xA, xxb, 3);
      else      k_prep<3, 4> <<<BD*ND/256, 256, 0, stream>>>(feat, xA, xxb, 0);
      knn(xA, CS0, 1);
      phA(xA, C0, CS0, 64, Wl[0], bl[0], gl[0], Bl[0]);
      k_phaseB<true,true><<<BD*ND/4, 256, 0, stream>>>(zs, cvb, idxb, xB, xxb, 64, 0, 0);
      // layer 1: 64 -> 128 (xx produced by phaseB)
      knn(xB, 64, 4);
      phA(xB, 64, 64, 128, Wl[1], bl[1], gl[1], Bl[1]);
      k_phaseB<true,true><<<BD*ND/4, 256, 0, stream>>>(zs, cvb, idxb, xA, xxb, 128, 0, 0);
      // layer 2: 128 -> 32, written into fuse at column offset (row-major)
      knn(xA, 128, 8);
      phA(xA, 128, 128, 32, Wl[2], bl[2], gl[2], Bl[2]);
      k_phaseB<false,false><<<BD*ND/4, 256, 0, stream>>>(zs, cvb, idxb, fuse, nullptr, 32, 64, part*32);
    }
    // MHA (flash-decode, no-max exp)
    k_lin<<<(BD*ND*192)/256, 256, 0, stream>>>(fuse, mha_wi, mha_bi, qkv);
    k_attn_part<<<BD*4*KSL, 256, 0, stream>>>(qkv, plb, paccb);
    k_attn_comb<<<(BD*8*ND)/256, 256, 0, stream>>>(plb, paccb, attno);
    k_projmean<<<(BD*ND*32)/256, 256, 0, stream>>>(attno, mha_wo, mha_bo, emb);
    // fused attention pool
    k_poolfuse<<<BD, 256, 0, stream>>>(emb, att_w, sout, pooled);
  }
  k_head<<<1, 256, 0, stream>>>(pool1, pool2, ntn_w, ntn_v, ntn_b,
                                fc1_w, fc1_b, sc_w, sc_b, out);
}

// Round 10
// 1192.659 us; speedup vs baseline: 1.7470x; 1.1585x over previous
//
#include <hip/hip_runtime.h>
#include <math.h>

#define BD 16      // fused batches: 2 branches x 8
#define ND 1024
#define KNN 20
#define NEGS 0.2f
#define BNSC 0.99999500003749969482f
#define KSL 8      // key slices for flash-decode attention
#define KPS 128    // keys per slice

__device__ __forceinline__ float leakyf(float y){ return y >= 0.f ? y : NEGS*y; }

// r10 structural change: the two independent branches are fused into ONE 16-batch
// pipeline (b16 = br*8 + b8). Every kernel maps b = blockIdx.x & 15; XCD = b&7
// automatically under round-robin dispatch (2 batches/XCD, ~2MB/XCD working set).
// knn grid doubles to 1024 blocks = 4 blocks/CU: independent blocks hide each
// other's stage-barrier stalls -- the TLP that intra-block pipelining (r1/r3/r4/
// r6/r9, all failed on registers or drain-bandwidth) could not buy. Launches 51->26.
// x buffers keep the knn-tiled layout x_t[b][g][n][4] (r5) and knn keeps the r7
// body (proven best: VGPR 72, 8-col chunks, LDS broadcast per r8 lesson).

// -------- fused input slice + transpose + xx: tiled write, both branches -------------
template<int C, int CS>
__global__ __launch_bounds__(256) void k_prep(const float* __restrict__ f1,
                                              const float* __restrict__ f2,
                                              float* __restrict__ x,
                                              float* __restrict__ xx, int c0){
  int blk = blockIdx.x;
  int b = blk & 15;
  int n = (blk >> 4)*256 + threadIdx.x;
  const float* feat = (b & 8) ? f2 : f1;
  int b8 = b & 7;
  float v[CS];
  float s = 0.f;
  #pragma unroll
  for (int c = 0; c < C; ++c){
    v[c] = feat[((size_t)(b8*15) + c0 + c)*ND + n];
    s = fmaf(v[c], v[c], s);
  }
  #pragma unroll
  for (int c = C; c < CS; ++c) v[c] = 0.f;
  #pragma unroll
  for (int g = 0; g < CS/4; ++g)
    *(float4*)&x[(size_t)(b*CS + g*4)*ND + (size_t)n*4] =
        make_float4(v[g*4], v[g*4+1], v[g*4+2], v[g*4+3]);
  xx[b*ND + n] = s;
}

// -------- fused gram + exact top-20 (r7 body; grid 1024 = 4 blocks/CU) ---------------
__global__ __launch_bounds__(256)
void k_knn(const float* __restrict__ x,
    const float* __restrict__ xx, int* __restrict__ idxp, int CS, int nchunk){
  __shared__ __align__(16) float Xc0[1024*4];   // 16 KB: cols, feature quad g0
  __shared__ __align__(16) float Xc1[1024*4];   // 16 KB: cols, feature quad g1
  int b = blockIdx.x & 15;
  int r0 = (blockIdx.x >> 4)*16;
  int t = threadIdx.x;
  int lane = t & 63;
  int w = __builtin_amdgcn_readfirstlane(t >> 6);   // wave-uniform wave id
  const float* xb = x + (size_t)b*ND*CS;            // tiled [G][n][4]
  float acc[4][16];
  #pragma unroll
  for (int j = 0; j < 4; ++j)
    #pragma unroll
    for (int q = 0; q < 16; ++q) acc[j][q] = 0.f;
  for (int ch = 0; ch < nchunk; ++ch){
    int g0 = 2*ch, g1 = 2*ch + 1;
    bool h1 = (g1*4 < CS);
    __syncthreads();
    for (int m = t; m < 1024; m += 256){
      // contiguous 16B/lane: lane t reads bytes [g*16K + m*16, +16)
      *(float4*)&Xc0[m*4] = *(const float4*)&xb[((size_t)g0*ND + m)*4];
      *(float4*)&Xc1[m*4] = h1 ? *(const float4*)&xb[((size_t)g1*ND + m)*4]
                               : make_float4(0.f,0.f,0.f,0.f);
    }
    __syncthreads();
    // row fragments from LDS (rows r0..r0+15 are columns; uniform-addr broadcast)
    float4 rv0[4], rv1[4];
    #pragma unroll
    for (int j = 0; j < 4; ++j){
      rv0[j] = *(const float4*)&Xc0[(r0 + w*4 + j)*4];
      rv1[j] = *(const float4*)&Xc1[(r0 + w*4 + j)*4];
    }
    #pragma unroll
    for (int q = 0; q < 16; ++q){
      float4 cv0 = *(const float4*)&Xc0[(q*64 + lane)*4];
      float4 cv1 = *(const float4*)&Xc1[(q*64 + lane)*4];
      #pragma unroll
      for (int j = 0; j < 4; ++j){
        float s = acc[j][q];   // strict sequential col order: bitwise-stable result
        s = fmaf(rv0[j].x, cv0.x, s); s = fmaf(rv0[j].y, cv0.y, s);
        s = fmaf(rv0[j].z, cv0.z, s); s = fmaf(rv0[j].w, cv0.w, s);
        s = fmaf(rv1[j].x, cv1.x, s); s = fmaf(rv1[j].y, cv1.y, s);
        s = fmaf(rv1[j].z, cv1.z, s); s = fmaf(rv1[j].w, cv1.w, s);
        acc[j][q] = s;
      }
    }
  }
  // transform to negdist = 2*dot - xx_r - xx_m, then to sortable uints
  float xxm[16];
  #pragma unroll
  for (int q = 0; q < 16; ++q) xxm[q] = xx[b*ND + q*64 + lane];
  unsigned uk[4][16];
  #pragma unroll
  for (int j = 0; j < 4; ++j){
    float xr = xx[b*ND + r0 + w*4 + j];
    #pragma unroll
    for (int q = 0; q < 16; ++q){
      float f = 2.f*acc[j][q] - xr - xxm[q];
      unsigned bv = __float_as_uint(f);
      uk[j][q] = (bv & 0x80000000u) ? ~bv : (bv | 0x80000000u);  // order-preserving
    }
  }
  // radix binary search for T = 20th-largest key per row (bit 31: only the diagonal
  // reaches it, count==1<20 always -> skip). Early exit at exact count==20 (set-equal).
  unsigned pref[4] = {0u, 0u, 0u, 0u};
  unsigned done = 0u;
  #pragma unroll 1
  for (int bit = 30; bit >= 0; --bit){
    #pragma unroll
    for (int u = 0; u < 4; ++u){
      if (done & (1u << u)) continue;           // wave-uniform (ballot-derived)
      unsigned cand = pref[u] | (1u << bit);
      int c = 0;
      #pragma unroll
      for (int q = 0; q < 16; ++q)
        c += (int)__popcll(__ballot(uk[u][q] >= cand));
      if (c >= KNN){
        pref[u] = cand;
        if (c == KNN) done |= (1u << u);
      }
    }
    if (done == 15u) break;
  }
  // emit: all keys > T, plus lowest-global-index keys == T to fill to 20
  unsigned long long mlt = (1ull << lane) - 1ull;   // lanes below me
  #pragma unroll
  for (int u = 0; u < 4; ++u){
    unsigned T = pref[u];
    int cg = 0;
    #pragma unroll
    for (int q = 0; q < 16; ++q) cg += (int)__popcll(__ballot(uk[u][q] > T));
    int need_eq = KNN - cg;                          // >= 1 by construction
    int* op = &idxp[((size_t)(b*ND + r0 + w*4 + u))*KNN];
    int run_gt = 0, run_eq = 0;
    #pragma unroll
    for (int q = 0; q < 16; ++q){
      unsigned k = uk[u][q];
      unsigned long long bg = __ballot(k > T);
      unsigned long long be = __ballot(k == T);
      if (k > T) op[run_gt + (int)__popcll(bg & mlt)] = q*64 + lane;
      if (k == T){
        int r = run_eq + (int)__popcll(be & mlt);
        if (r < need_eq) op[cg + r] = q*64 + lane;
      }
      run_gt += (int)__popcll(bg);
      run_eq += (int)__popcll(be);
    }
  }
}

// ------ phase A (register-blocked), tiled x, 16 batches (grid 512 = 2 blocks/CU) -----
template<int O>
__global__ __launch_bounds__(256) void k_phaseA(const float* __restrict__ x,
    const float* __restrict__ W, const float* __restrict__ bias,
    const float* __restrict__ gamma, const float* __restrict__ beta,
    float* __restrict__ zs, float* __restrict__ ccv, int C, int XS){
  constexpr int TO = O/16;
  constexpr int WP = O + 4;
  __shared__ float W1s[32*WP];
  __shared__ float dWs[32*WP];
  __shared__ float Xs[32*33];
  int blk = blockIdx.x;
  int b = blk & 15, n0 = (blk >> 4)*32;
  int t = threadIdx.x;
  int ot = t & 15, nt = t >> 4;
  int obase = ot*TO;
  int nl = nt*2;
  float az[TO][2] = {}, ac[TO][2] = {};
  for (int cc = 0; cc < C; cc += 32){
    int KC = (C - cc < 32) ? (C - cc) : 32;
    int NG = (KC + 3) >> 2;
    for (int i = t; i < O*KC; i += 256){
      int o = i % O, c = i / O;
      float w1 = W[(size_t)o*2*C + cc + c];
      float w2 = W[(size_t)o*2*C + C + cc + c];
      W1s[c*WP + o] = w1;
      dWs[c*WP + o] = w2 - w1;
    }
    for (int i = t; i < 32*NG; i += 256){
      int row = i & 31, g = i >> 5;
      float4 v = *(const float4*)&x[(size_t)(b*XS + cc + g*4)*ND + (size_t)(n0+row)*4];
      Xs[(g*4+0)*33 + row] = v.x;
      Xs[(g*4+1)*33 + row] = v.y;
      Xs[(g*4+2)*33 + row] = v.z;
      Xs[(g*4+3)*33 + row] = v.w;
    }
    __syncthreads();
    for (int c = 0; c < KC; ++c){
      float xv0 = Xs[c*33 + nl];
      float xv1 = Xs[c*33 + nl + 1];
      #pragma unroll
      for (int i = 0; i < TO; ++i){
        float w1 = W1s[c*WP + obase + i];
        float dw = dWs[c*WP + obase + i];
        az[i][0] = fmaf(w1, xv0, az[i][0]);
        az[i][1] = fmaf(w1, xv1, az[i][1]);
        ac[i][0] = fmaf(dw, xv0, ac[i][0]);
        ac[i][1] = fmaf(dw, xv1, ac[i][1]);
      }
    }
    __syncthreads();
  }
  #pragma unroll
  for (int i = 0; i < TO; ++i){
    int o = obase + i;
    float alpha = gamma[o]*BNSC;
    float bb = bias[o], be = beta[o];
    #pragma unroll
    for (int q = 0; q < 2; ++q){
      int n = n0 + nl + q;
      size_t off = ((size_t)b*ND + n)*O + o;
      zs[off]  = az[i][q]*alpha;
      ccv[off] = fmaf(ac[i][q] + bb, alpha, be);
    }
  }
}

// ------ phase B: out = max_k leaky(zs[idx_k]+cc); TILED knn-layout writes ------------
template<bool DOXX, bool TILED>
__global__ __launch_bounds__(256) void k_phaseB(const float* __restrict__ zs,
    const float* __restrict__ ccv, const int* __restrict__ idxp,
    float* __restrict__ outp, float* __restrict__ xxout,
    int O, int ostride, int ooff){
  int t = threadIdx.x;
  int lane = t & 63, w = t >> 6;
  int b = blockIdx.x & 15;
  int n = (blockIdx.x >> 4)*4 + w;
  int gn = (b << 10) + n;
  int mm[KNN];
  const int* ip = idxp + (size_t)gn*KNN;
  #pragma unroll
  for (int k = 0; k < KNN; ++k) mm[k] = ip[k];
  float sq = 0.f;
  for (int o = lane; o < O; o += 64){
    float cvv = ccv[(size_t)gn*O + o];
    float mx = -INFINITY;
    #pragma unroll 4
    for (int k = 0; k < KNN; ++k){
      float v = leakyf(zs[((size_t)(b*ND) + mm[k])*O + o] + cvv);
      mx = fmaxf(mx, v);
    }
    if (TILED)
      outp[(size_t)(b*O + (o & ~3))*ND + (size_t)n*4 + (o & 3)] = mx;
    else
      outp[(size_t)gn*ostride + ooff + o] = mx;
    if (DOXX) sq = fmaf(mx, mx, sq);
  }
  if (DOXX){
    #pragma unroll
    for (int off = 32; off; off >>= 1) sq += __shfl_down(sq, off);
    if (lane == 0) xxout[gn] = sq;
  }
}

// --------- qkv[bn,o] = fuse[bn,:].Wi[o,:] + bi[o]  (raw Wi, float4) ------------------
__global__ __launch_bounds__(256) void k_lin(const float* __restrict__ in,
    const float* __restrict__ Wm, const float* __restrict__ bias,
    float* __restrict__ outp){
  int b = blockIdx.x & 15;
  int inner = (blockIdx.x >> 4)*256 + threadIdx.x;   // 0..196607
  int o = inner % 192; int n = inner / 192;
  int bn = (b << 10) + n;
  const float4* ip = (const float4*)(in + (size_t)bn*64);
  const float4* wp = (const float4*)(Wm + (size_t)o*64);
  float s = bias[o];
  #pragma unroll
  for (int c = 0; c < 16; ++c){
    float4 a = ip[c], wv = wp[c];
    s = fmaf(a.x, wv.x, s); s = fmaf(a.y, wv.y, s);
    s = fmaf(a.z, wv.z, s); s = fmaf(a.w, wv.w, s);
  }
  outp[(size_t)bn*192 + o] = s;
}

// ------- flash-decode attention (no-max exp): 2 heads/block ---------------------------
__global__ __launch_bounds__(256, 1) void k_attn_part(const float* __restrict__ qkv,
    float* __restrict__ pl, float* __restrict__ pacc){
  __shared__ __align__(16) float Ks[2][KPS*8];
  __shared__ __align__(16) float Vs[2][KPS*8];
  int blk = blockIdx.x;                // b(16, low bits) x ksl(8) x hp(4) = 512 blocks
  int b = blk & 15; int ksl = (blk >> 4) & 7; int hp = blk >> 7;
  int t = threadIdx.x;
  int hh = t >> 7;                     // wave-uniform head select within pair
  int h = hp*2 + hh;
  int lq = t & 127;
  for (int i = t; i < 2*KPS*8; i += 256){
    int hi = (i >= KPS*8) ? 1 : 0;
    int r = i - hi*KPS*8;
    int m = r >> 3, dd = r & 7;
    size_t base = ((size_t)b*ND + ksl*KPS + m)*192 + (hp*2 + hi)*8 + dd;
    Ks[hi][r] = qkv[base + 64];
    Vs[hi][r] = qkv[base + 128];
  }
  __syncthreads();
  const float scale = 0.35355339059327373f;
  float q[8][8];
  #pragma unroll
  for (int u = 0; u < 8; ++u){
    int n = u*128 + lq;
    const float4* qp = (const float4*)(qkv + ((size_t)b*ND + n)*192 + h*8);
    float4 q0 = qp[0], q1 = qp[1];
    q[u][0]=q0.x*scale; q[u][1]=q0.y*scale; q[u][2]=q0.z*scale; q[u][3]=q0.w*scale;
    q[u][4]=q1.x*scale; q[u][5]=q1.y*scale; q[u][6]=q1.z*scale; q[u][7]=q1.w*scale;
  }
  float l[8] = {};
  float acc[8][8] = {};
  for (int m = 0; m < KPS; ++m){
    float4 k0 = *(const float4*)&Ks[hh][m*8];
    float4 k1 = *(const float4*)&Ks[hh][m*8+4];
    float4 v0 = *(const float4*)&Vs[hh][m*8];
    float4 v1 = *(const float4*)&Vs[hh][m*8+4];
    #pragma unroll
    for (int u = 0; u < 8; ++u){
      float s;
      s = q[u][0]*k0.x;           s = fmaf(q[u][1], k0.y, s);
      s = fmaf(q[u][2], k0.z, s); s = fmaf(q[u][3], k0.w, s);
      s = fmaf(q[u][4], k1.x, s); s = fmaf(q[u][5], k1.y, s);
      s = fmaf(q[u][6], k1.z, s); s = fmaf(q[u][7], k1.w, s);
      float p = __expf(s);        // scores tiny: exp-without-max is safe; merge = sum
      l[u] += p;
      acc[u][0] = fmaf(p, v0.x, acc[u][0]);
      acc[u][1] = fmaf(p, v0.y, acc[u][1]);
      acc[u][2] = fmaf(p, v0.z, acc[u][2]);
      acc[u][3] = fmaf(p, v0.w, acc[u][3]);
      acc[u][4] = fmaf(p, v1.x, acc[u][4]);
      acc[u][5] = fmaf(p, v1.y, acc[u][5]);
      acc[u][6] = fmaf(p, v1.z, acc[u][6]);
      acc[u][7] = fmaf(p, v1.w, acc[u][7]);
    }
  }
  #pragma unroll
  for (int u = 0; u < 8; ++u){
    int n = u*128 + lq;
    size_t pidx = (((size_t)(b*8 + h))*8 + ksl)*ND + n;
    pl[pidx] = l[u];
    float4* ap = (float4*)&pacc[pidx*8];
    ap[0] = make_float4(acc[u][0], acc[u][1], acc[u][2], acc[u][3]);
    ap[1] = make_float4(acc[u][4], acc[u][5], acc[u][6], acc[u][7]);
  }
}

// ------- flash-decode combine: plain sums --------------------------------------------
__global__ __launch_bounds__(256) void k_attn_comb(const float* __restrict__ pl,
    const float* __restrict__ pacc, float* __restrict__ attno){
  int b = blockIdx.x & 15;
  int inner = (blockIdx.x >> 4)*256 + threadIdx.x;   // 0..8191 = h(8) x n(1024)
  int h = inner >> 10; int n = inner & 1023;
  int bh = b*8 + h;
  float L = 0.f;
  float o[8] = {};
  #pragma unroll
  for (int s = 0; s < KSL; ++s){
    size_t pidx = ((size_t)bh*8 + s)*ND + n;
    L += pl[pidx];
    const float4* ap = (const float4*)&pacc[pidx*8];
    float4 a0 = ap[0], a1 = ap[1];
    o[0] += a0.x; o[1] += a0.y; o[2] += a0.z; o[3] += a0.w;
    o[4] += a1.x; o[5] += a1.y; o[6] += a1.z; o[7] += a1.w;
  }
  float inv = 1.f/L;
  float4* dst = (float4*)&attno[((size_t)b*ND + n)*64 + h*8];
  dst[0] = make_float4(o[0]*inv, o[1]*inv, o[2]*inv, o[3]*inv);
  dst[1] = make_float4(o[4]*inv, o[5]*inv, o[6]*inv, o[7]*inv);
}

// ------- out-proj + pair-mean: emb[bn,f] = 0.5*(proj[2f]+proj[2f+1]) -----------------
__global__ __launch_bounds__(256) void k_projmean(const float* __restrict__ attno,
    const float* __restrict__ Wo, const float* __restrict__ bo,
    float* __restrict__ emb){
  int b = blockIdx.x & 15;
  int inner = (blockIdx.x >> 4)*256 + threadIdx.x;   // 0..32767 = n(1024) x f(32)
  int n = inner >> 5; int f = inner & 31;
  int bn = (b << 10) + n;
  const float4* ip = (const float4*)(attno + (size_t)bn*64);
  int o0 = 2*f, o1 = 2*f + 1;
  const float4* w0 = (const float4*)(Wo + (size_t)o0*64);
  const float4* w1 = (const float4*)(Wo + (size_t)o1*64);
  float s0 = bo[o0], s1 = bo[o1];
  #pragma unroll
  for (int c = 0; c < 16; ++c){
    float4 a = ip[c], u = w0[c], v = w1[c];
    s0 = fmaf(a.x,u.x,s0); s0 = fmaf(a.y,u.y,s0); s0 = fmaf(a.z,u.z,s0); s0 = fmaf(a.w,u.w,s0);
    s1 = fmaf(a.x,v.x,s1); s1 = fmaf(a.y,v.y,s1); s1 = fmaf(a.z,v.z,s1); s1 = fmaf(a.w,v.w,s1);
  }
  emb[(size_t)bn*32 + f] = 0.5f*(s0 + s1);
}

// ---------------- fused attention pool: one block per b16 ----------------------------
// sout base = out+8; b16*ND+n == br*(8*ND)+b8*ND+n (branch output slices contiguous)
__global__ __launch_bounds__(256) void k_poolfuse(const float* __restrict__ emb,
    const float* __restrict__ attw, float* __restrict__ sout,
    float* __restrict__ pooled){
  __shared__ float part[8][32];
  __shared__ float meanv[32];
  __shared__ float gv[32];
  __shared__ float sc[ND];
  int b = blockIdx.x, t = threadIdx.x;
  int f = t & 31, j = t >> 5;
  const float* eb = emb + (size_t)b*ND*32;
  float s = 0.f;
  for (int n = j; n < ND; n += 8) s += eb[n*32 + f];
  part[j][f] = s;
  __syncthreads();
  if (t < 32){
    float m = 0.f;
    for (int j2 = 0; j2 < 8; ++j2) m += part[j2][t];
    meanv[t] = m * (1.f/ND);
  }
  __syncthreads();
  if (t < 32){
    float acc = 0.f;
    for (int f2 = 0; f2 < 32; ++f2) acc = fmaf(meanv[f2], attw[f2*32 + t], acc);
    gv[t] = tanhf(acc);
  }
  __syncthreads();
  for (int n = t; n < ND; n += 256){
    const float4* ep = (const float4*)(eb + n*32);
    float acc = 0.f;
    #pragma unroll
    for (int f4 = 0; f4 < 8; ++f4){
      float4 e = ep[f4];
      acc = fmaf(e.x, gv[f4*4+0], acc);
      acc = fmaf(e.y, gv[f4*4+1], acc);
      acc = fmaf(e.z, gv[f4*4+2], acc);
      acc = fmaf(e.w, gv[f4*4+3], acc);
    }
    float sg = 1.f/(1.f + __expf(-acc));
    sout[(size_t)b*ND + n] = sg;
    sc[n] = sg;
  }
  __syncthreads();
  float pacc = 0.f;
  for (int n = j; n < ND; n += 8) pacc = fmaf(eb[n*32 + f], sc[n], pacc);
  part[j][f] = pacc;
  __syncthreads();
  if (t < 32){
    float m = 0.f;
    for (int j2 = 0; j2 < 8; ++j2) m += part[j2][t];
    pooled[b*32 + t] = m;
  }
}

// ---------------- NTN head: LDS-staged weights (2-phase, 32KB each) ------------------
__global__ __launch_bounds__(256) void k_head(const float* __restrict__ p1,
    const float* __restrict__ p2, const float* __restrict__ ntnw,
    const float* __restrict__ ntnv, const float* __restrict__ ntnb,
    const float* __restrict__ fc1w, const float* __restrict__ fc1b,
    const float* __restrict__ scw, const float* __restrict__ scb,
    float* __restrict__ outscore){
  __shared__ __align__(16) float Wl[8192];
  __shared__ float Vl[512];
  __shared__ float F1[256];
  __shared__ float ds[8][32];
  __shared__ float tv[8][16];
  __shared__ float hv[8][16];
  int t = threadIdx.x;
  {
    int b = t >> 5, f = t & 31;
    ds[b][f] = p1[b*32+f] - p2[b*32+f];
  }
  for (int i = t; i < 512; i += 256) Vl[i] = ntnv[i];
  if (t < 256) F1[t] = fc1w[t];
  float acc = 0.f;
  for (int ph = 0; ph < 2; ++ph){
    __syncthreads();
    {
      const float4* src = (const float4*)(ntnw + ph*8192);
      float4* dst = (float4*)Wl;
      for (int i = t; i < 2048; i += 256) dst[i] = src[i];
    }
    __syncthreads();
    if (t < 128){
      int b = t >> 4, tt = t & 15;
      for (int fi = 0; fi < 16; ++fi){
        float df = ds[b][ph*16 + fi];
        #pragma unroll 8
        for (int gg = 0; gg < 32; ++gg)
          acc = fmaf(df*ds[b][gg], Wl[(fi*32+gg)*16 + tt], acc);
      }
    }
  }
  if (t < 128){
    int b = t >> 4, tt = t & 15;
    acc += ntnb[tt];
    for (int gg = 0; gg < 32; ++gg) acc = fmaf(ds[b][gg], Vl[tt*32+gg], acc);
    tv[b][tt] = fmaxf(acc, 0.f);
  }
  __syncthreads();
  if (t < 128){
    int b = t >> 4, i = t & 15;
    float a2 = fc1b[i];
    for (int kk = 0; kk < 16; ++kk) a2 = fmaf(tv[b][kk], F1[i*16+kk], a2);
    hv[b][i] = fmaxf(a2, 0.f);
  }
  __syncthreads();
  if (t < 8){
    float a3 = scb[0];
    for (int i = 0; i < 16; ++i) a3 = fmaf(hv[t][i], scw[i], a3);
    outscore[t] = 1.f/(1.f + __expf(-a3));
  }
}

// =====================================================================================
extern "C" void kernel_launch(void* const* d_in, const int* in_sizes, int n_in,
                              void* d_out, int out_size, void* d_ws, size_t ws_size,
                              hipStream_t stream) {
  auto F = [&](int i){ return (const float*)d_in[i]; };
  const float* f1 = F(0); const float* f2 = F(1);
  const float* cw[3] = { F(2), F(6), F(10) };
  const float* cb[3] = { F(3), F(7), F(11) };
  const float* cg[3] = { F(4), F(8), F(12) };
  const float* cB[3] = { F(5), F(9), F(13) };
  const float* sw[3] = { F(14), F(18), F(22) };
  const float* sb[3] = { F(15), F(19), F(23) };
  const float* sg[3] = { F(16), F(20), F(24) };
  const float* sB[3] = { F(17), F(21), F(25) };
  const float* mha_wi = F(26); const float* mha_bi = F(27);
  const float* mha_wo = F(28); const float* mha_bo = F(29);
  const float* att_w  = F(30);
  const float* ntn_w  = F(31); const float* ntn_v = F(32); const float* ntn_b = F(33);
  const float* fc1_w  = F(34); const float* fc1_b = F(35);
  const float* sc_w   = F(36); const float* sc_b  = F(37);
  float* out = (float*)d_out;

  char* ws = (char*)d_ws;
  const size_t MB = 1 << 20;
  // Edge-conv segment [0, 35MB) -- dead before the MHA phase begins:
  float* xA   = (float*)(ws + 0*MB);        // 8 MB  (16 x 1024 x 128 x 4)
  float* xB   = (float*)(ws + 8*MB);        // 8 MB
  float* zs   = (float*)(ws + 16*MB);       // 8 MB
  float* cvb  = (float*)(ws + 24*MB);       // 8 MB
  int*   idxb = (int*)  (ws + 32*MB);       // 1.25 MB
  float* xxb  = (float*)(ws + 34*MB);       // 64 KB
  float* fuse = (float*)(ws + 35*MB);       // 4 MB  [dies after k_lin]
  // MHA segment aliases the dead edge-conv buffers (stream-sequential, safe):
  float* qkv   = (float*)(ws + 0*MB);       // 12 MB over xA + xB-low   (dead)
  float* plb   = (float*)(ws + 12*MB);      // 4 MB  over xB-high       (dead)
  float* paccb = (float*)(ws + 16*MB);      // 32 MB over zs,cvb,idx,xx,fuse (dead)
  float* attno = (float*)(ws + 48*MB);      // 4 MB fresh
  float* emb   = (float*)(ws + 52*MB);      // 2 MB fresh
  float* pooled= (float*)(ws + 54*MB);      // 2 KB
  (void)ws_size;

  auto knn = [&](const float* xin, int CS, int nch8){
    k_knn<<<BD*64, 256, 0, stream>>>(xin, xxb, idxb, CS, nch8);
  };
  auto phA = [&](const float* xin, int C, int XS, int O, const float* W, const float* bb,
                 const float* gg, const float* be){
    if (O == 64)       k_phaseA<64> <<<BD*32, 256, 0, stream>>>(xin, W, bb, gg, be, zs, cvb, C, XS);
    else if (O == 128) k_phaseA<128><<<BD*32, 256, 0, stream>>>(xin, W, bb, gg, be, zs, cvb, C, XS);
    else               k_phaseA<32> <<<BD*32, 256, 0, stream>>>(xin, W, bb, gg, be, zs, cvb, C, XS);
  };

  for (int part = 0; part < 2; ++part){
    const float* const* Wl = part ? sw : cw;
    const float* const* bl = part ? sb : cb;
    const float* const* gl = part ? sg : cg;
    const float* const* Bl = part ? sB : cB;
    int C0 = part ? 12 : 3;
    int CS0 = part ? 12 : 4;
    // layer 0: C0 -> 64 (both branches at once: 16 batches)
    if (part) k_prep<12,12><<<BD*ND/256, 256, 0, stream>>>(f1, f2, xA, xxb, 3);
    else      k_prep<3, 4> <<<BD*ND/256, 256, 0, stream>>>(f1, f2, xA, xxb, 0);
    knn(xA, CS0, part ? 2 : 1);
    phA(xA, C0, CS0, 64, Wl[0], bl[0], gl[0], Bl[0]);
    k_phaseB<true,true><<<BD*ND/4, 256, 0, stream>>>(zs, cvb, idxb, xB, xxb, 64, 0, 0);
    // layer 1: 64 -> 128 (xx produced by phaseB)
    knn(xB, 64, 8);
    phA(xB, 64, 64, 128, Wl[1], bl[1], gl[1], Bl[1]);
    k_phaseB<true,true><<<BD*ND/4, 256, 0, stream>>>(zs, cvb, idxb, xA, xxb, 128, 0, 0);
    // layer 2: 128 -> 32, written into fuse at column offset (row-major)
    knn(xA, 128, 16);
    phA(xA, 128, 128, 32, Wl[2], bl[2], gl[2], Bl[2]);
    k_phaseB<false,false><<<BD*ND/4, 256, 0, stream>>>(zs, cvb, idxb, fuse, nullptr, 32, 64, part*32);
  }
  // MHA (flash-decode, no-max exp) over all 16 batches
  k_lin<<<(BD*ND*192)/256, 256, 0, stream>>>(fuse, mha_wi, mha_bi, qkv);
  k_attn_part<<<BD*4*KSL, 256, 0, stream>>>(qkv, plb, paccb);
  k_attn_comb<<<(BD*8*ND)/256, 256, 0, stream>>>(plb, paccb, attno);
  k_projmean<<<(BD*ND*32)/256, 256, 0, stream>>>(attno, mha_wo, mha_bo, emb);
  // fused attention pool (sout slices are contiguous across the 16 batches)
  k_poolfuse<<<BD, 256, 0, stream>>>(emb, att_w, out + 8, pooled);
  k_head<<<1, 256, 0, stream>>>(pooled, pooled + 256, ntn_w, ntn_v, ntn_b,
                                fc1_w, fc1_b, sc_w, sc_b, out);
}

// Round 12
// 1102.616 us; speedup vs baseline: 1.8897x; 1.0817x over previous
//
#include <hip/hip_runtime.h>
#include <math.h>

#define BD 16      // fused batches: 2 branches x 8
#define ND 1024
#define KNN 20
#define NEGS 0.2f
#define BNSC 0.99999500003749969482f
#define KSL 8      // key slices for flash-decode attention
#define KPS 128    // keys per slice

__device__ __forceinline__ float leakyf(float y){ return y >= 0.f ? y : NEGS*y; }

// async global->LDS DMA, 16B per lane: dest = wave-uniform base + lane*16 (HW rule),
// src = per-lane. With the tiled x layout the src is lane-CONTIGUOUS (1KB/instr) --
// this removes r3's failure cause (a): its row-major src was a 64-line scatter.
__device__ __forceinline__ void gl_lds16(const float* g, float* l){
  __builtin_amdgcn_global_load_lds(
      (const __attribute__((address_space(1))) void*)g,
      (__attribute__((address_space(3))) void*)l, 16, 0, 0);
}

// r12 == r11 resubmitted (round-11 bench died at container bringup, no kernel verdict).
// knn staging = global_load_lds ping-pong. r3's two failure causes are gone:
// (a) tiled layout -> contiguous DMA src; (b) rows come from LDS (r5) -> ZERO
// prefetch VGPRs (r3 burned 48 on row prefetch and spilled). Flow per chunk:
// issue DMA for ch+1 into idle buf (background, no VALU/VGPR cost) -> compute ch from
// LDS -> ONE barrier (vmcnt drain free: loads had the ~1400cy FMA phase to land).
// Replaces r7/r10's serialized barrier->load(latency exposed)->ds_write->barrier.

// -------- fused input slice + transpose + xx: tiled write, both branches -------------
template<int C, int CS>
__global__ __launch_bounds__(256) void k_prep(const float* __restrict__ f1,
                                              const float* __restrict__ f2,
                                              float* __restrict__ x,
                                              float* __restrict__ xx, int c0){
  int blk = blockIdx.x;
  int b = blk & 15;
  int n = (blk >> 4)*256 + threadIdx.x;
  const float* feat = (b & 8) ? f2 : f1;
  int b8 = b & 7;
  float v[CS];
  float s = 0.f;
  #pragma unroll
  for (int c = 0; c < C; ++c){
    v[c] = feat[((size_t)(b8*15) + c0 + c)*ND + n];
    s = fmaf(v[c], v[c], s);
  }
  #pragma unroll
  for (int c = C; c < CS; ++c) v[c] = 0.f;
  #pragma unroll
  for (int g = 0; g < CS/4; ++g)
    *(float4*)&x[(size_t)(b*CS + g*4)*ND + (size_t)n*4] =
        make_float4(v[g*4], v[g*4+1], v[g*4+2], v[g*4+3]);
  xx[b*ND + n] = s;
}

// -------- fused gram + exact top-20: DMA ping-pong staging ---------------------------
__global__ __launch_bounds__(256)
void k_knn(const float* __restrict__ x,
    const float* __restrict__ xx, int* __restrict__ idxp, int CS, int nchunk){
  __shared__ __align__(16) float Xc[2][2][4096];   // [buf][quad-array][1024*4] = 64KB
  int b = blockIdx.x & 15;
  int r0 = (blockIdx.x >> 4)*16;
  int t = threadIdx.x;
  int lane = t & 63;
  int w = __builtin_amdgcn_readfirstlane(t >> 6);   // wave-uniform wave id
  const float* xb = x + (size_t)b*ND*CS;            // tiled [G][n][4]
  float acc[4][16];
  #pragma unroll
  for (int j = 0; j < 4; ++j)
    #pragma unroll
    for (int q = 0; q < 16; ++q) acc[j][q] = 0.f;

  // stage chunk ch (quads 2ch, 2ch+1) into buffer buf via DMA; zero-fill padded quads
  auto stage = [&](int buf, int ch){
    int g0 = 2*ch, g1 = 2*ch + 1;
    bool v1 = (g1*4 < CS);                       // g0 always valid by construction
    #pragma unroll
    for (int i = 0; i < 4; ++i){
      int m = i*256 + t;
      unsigned ub = (unsigned)((i*256 + (w << 6))*4);   // wave-uniform elem base
      gl_lds16(&xb[((size_t)g0*ND + m)*4], &Xc[buf][0][ub]);
      if (v1) gl_lds16(&xb[((size_t)g1*ND + m)*4], &Xc[buf][1][ub]);
      else    *(float4*)&Xc[buf][1][m*4] = make_float4(0.f,0.f,0.f,0.f);
    }
  };

  stage(0, 0);
  __syncthreads();              // drains vmcnt: buffer 0 ready
  int cur = 0;
  for (int ch = 0; ch < nchunk; ++ch){
    bool more = (ch + 1 < nchunk);
    if (more) stage(cur ^ 1, ch + 1);   // DMA in flight during the FMA phase
    // row fragments from LDS (rows r0..r0+15 are columns; uniform-addr broadcast)
    float4 rv0[4], rv1[4];
    #pragma unroll
    for (int j = 0; j < 4; ++j){
      rv0[j] = *(const float4*)&Xc[cur][0][(r0 + w*4 + j)*4];
      rv1[j] = *(const float4*)&Xc[cur][1][(r0 + w*4 + j)*4];
    }
    #pragma unroll
    for (int q = 0; q < 16; ++q){
      float4 cv0 = *(const float4*)&Xc[cur][0][(q*64 + lane)*4];
      float4 cv1 = *(const float4*)&Xc[cur][1][(q*64 + lane)*4];
      #pragma unroll
      for (int j = 0; j < 4; ++j){
        float s = acc[j][q];   // strict sequential col order: bitwise-stable result
        s = fmaf(rv0[j].x, cv0.x, s); s = fmaf(rv0[j].y, cv0.y, s);
        s = fmaf(rv0[j].z, cv0.z, s); s = fmaf(rv0[j].w, cv0.w, s);
        s = fmaf(rv1[j].x, cv1.x, s); s = fmaf(rv1[j].y, cv1.y, s);
        s = fmaf(rv1[j].z, cv1.z, s); s = fmaf(rv1[j].w, cv1.w, s);
        acc[j][q] = s;
      }
    }
    if (more){
      __syncthreads();   // all waves done reading cur; my ch+1 DMA drained (had
      cur ^= 1;          // the full FMA phase to land) -> idle buf ready
    }
  }
  // transform to negdist = 2*dot - xx_r - xx_m, then to sortable uints
  float xxm[16];
  #pragma unroll
  for (int q = 0; q < 16; ++q) xxm[q] = xx[b*ND + q*64 + lane];
  unsigned uk[4][16];
  #pragma unroll
  for (int j = 0; j < 4; ++j){
    float xr = xx[b*ND + r0 + w*4 + j];
    #pragma unroll
    for (int q = 0; q < 16; ++q){
      float f = 2.f*acc[j][q] - xr - xxm[q];
      unsigned bv = __float_as_uint(f);
      uk[j][q] = (bv & 0x80000000u) ? ~bv : (bv | 0x80000000u);  // order-preserving
    }
  }
  // radix binary search for T = 20th-largest key per row (bit 31: only the diagonal
  // reaches it, count==1<20 always -> skip). Early exit at exact count==20 (set-equal).
  unsigned pref[4] = {0u, 0u, 0u, 0u};
  unsigned done = 0u;
  #pragma unroll 1
  for (int bit = 30; bit >= 0; --bit){
    #pragma unroll
    for (int u = 0; u < 4; ++u){
      if (done & (1u << u)) continue;           // wave-uniform (ballot-derived)
      unsigned cand = pref[u] | (1u << bit);
      int c = 0;
      #pragma unroll
      for (int q = 0; q < 16; ++q)
        c += (int)__popcll(__ballot(uk[u][q] >= cand));
      if (c >= KNN){
        pref[u] = cand;
        if (c == KNN) done |= (1u << u);
      }
    }
    if (done == 15u) break;
  }
  // emit: all keys > T, plus lowest-global-index keys == T to fill to 20
  unsigned long long mlt = (1ull << lane) - 1ull;   // lanes below me
  #pragma unroll
  for (int u = 0; u < 4; ++u){
    unsigned T = pref[u];
    int cg = 0;
    #pragma unroll
    for (int q = 0; q < 16; ++q) cg += (int)__popcll(__ballot(uk[u][q] > T));
    int need_eq = KNN - cg;                          // >= 1 by construction
    int* op = &idxp[((size_t)(b*ND + r0 + w*4 + u))*KNN];
    int run_gt = 0, run_eq = 0;
    #pragma unroll
    for (int q = 0; q < 16; ++q){
      unsigned k = uk[u][q];
      unsigned long long bg = __ballot(k > T);
      unsigned long long be = __ballot(k == T);
      if (k > T) op[run_gt + (int)__popcll(bg & mlt)] = q*64 + lane;
      if (k == T){
        int r = run_eq + (int)__popcll(be & mlt);
        if (r < need_eq) op[cg + r] = q*64 + lane;
      }
      run_gt += (int)__popcll(bg);
      run_eq += (int)__popcll(be);
    }
  }
}

// ------ phase A (register-blocked), tiled x, 16 batches (grid 512 = 2 blocks/CU) -----
template<int O>
__global__ __launch_bounds__(256) void k_phaseA(const float* __restrict__ x,
    const float* __restrict__ W, const float* __restrict__ bias,
    const float* __restrict__ gamma, const float* __restrict__ beta,
    float* __restrict__ zs, float* __restrict__ ccv, int C, int XS){
  constexpr int TO = O/16;
  constexpr int WP = O + 4;
  __shared__ float W1s[32*WP];
  __shared__ float dWs[32*WP];
  __shared__ float Xs[32*33];
  int blk = blockIdx.x;
  int b = blk & 15, n0 = (blk >> 4)*32;
  int t = threadIdx.x;
  int ot = t & 15, nt = t >> 4;
  int obase = ot*TO;
  int nl = nt*2;
  float az[TO][2] = {}, ac[TO][2] = {};
  for (int cc = 0; cc < C; cc += 32){
    int KC = (C - cc < 32) ? (C - cc) : 32;
    int NG = (KC + 3) >> 2;
    for (int i = t; i < O*KC; i += 256){
      int o = i % O, c = i / O;
      float w1 = W[(size_t)o*2*C + cc + c];
      float w2 = W[(size_t)o*2*C + C + cc + c];
      W1s[c*WP + o] = w1;
      dWs[c*WP + o] = w2 - w1;
    }
    for (int i = t; i < 32*NG; i += 256){
      int row = i & 31, g = i >> 5;
      float4 v = *(const float4*)&x[(size_t)(b*XS + cc + g*4)*ND + (size_t)(n0+row)*4];
      Xs[(g*4+0)*33 + row] = v.x;
      Xs[(g*4+1)*33 + row] = v.y;
      Xs[(g*4+2)*33 + row] = v.z;
      Xs[(g*4+3)*33 + row] = v.w;
    }
    __syncthreads();
    for (int c = 0; c < KC; ++c){
      float xv0 = Xs[c*33 + nl];
      float xv1 = Xs[c*33 + nl + 1];
      #pragma unroll
      for (int i = 0; i < TO; ++i){
        float w1 = W1s[c*WP + obase + i];
        float dw = dWs[c*WP + obase + i];
        az[i][0] = fmaf(w1, xv0, az[i][0]);
        az[i][1] = fmaf(w1, xv1, az[i][1]);
        ac[i][0] = fmaf(dw, xv0, ac[i][0]);
        ac[i][1] = fmaf(dw, xv1, ac[i][1]);
      }
    }
    __syncthreads();
  }
  #pragma unroll
  for (int i = 0; i < TO; ++i){
    int o = obase + i;
    float alpha = gamma[o]*BNSC;
    float bb = bias[o], be = beta[o];
    #pragma unroll
    for (int q = 0; q < 2; ++q){
      int n = n0 + nl + q;
      size_t off = ((size_t)b*ND + n)*O + o;
      zs[off]  = az[i][q]*alpha;
      ccv[off] = fmaf(ac[i][q] + bb, alpha, be);
    }
  }
}

// ------ phase B: out = max_k leaky(zs[idx_k]+cc); TILED knn-layout writes ------------
template<bool DOXX, bool TILED>
__global__ __launch_bounds__(256) void k_phaseB(const float* __restrict__ zs,
    const float* __restrict__ ccv, const int* __restrict__ idxp,
    float* __restrict__ outp, float* __restrict__ xxout,
    int O, int ostride, int ooff){
  int t = threadIdx.x;
  int lane = t & 63, w = t >> 6;
  int b = blockIdx.x & 15;
  int n = (blockIdx.x >> 4)*4 + w;
  int gn = (b << 10) + n;
  int mm[KNN];
  const int* ip = idxp + (size_t)gn*KNN;
  #pragma unroll
  for (int k = 0; k < KNN; ++k) mm[k] = ip[k];
  float sq = 0.f;
  for (int o = lane; o < O; o += 64){
    float cvv = ccv[(size_t)gn*O + o];
    float mx = -INFINITY;
    #pragma unroll 4
    for (int k = 0; k < KNN; ++k){
      float v = leakyf(zs[((size_t)(b*ND) + mm[k])*O + o] + cvv);
      mx = fmaxf(mx, v);
    }
    if (TILED)
      outp[(size_t)(b*O + (o & ~3))*ND + (size_t)n*4 + (o & 3)] = mx;
    else
      outp[(size_t)gn*ostride + ooff + o] = mx;
    if (DOXX) sq = fmaf(mx, mx, sq);
  }
  if (DOXX){
    #pragma unroll
    for (int off = 32; off; off >>= 1) sq += __shfl_down(sq, off);
    if (lane == 0) xxout[gn] = sq;
  }
}

// --------- qkv[bn,o] = fuse[bn,:].Wi[o,:] + bi[o]  (raw Wi, float4) ------------------
__global__ __launch_bounds__(256) void k_lin(const float* __restrict__ in,
    const float* __restrict__ Wm, const float* __restrict__ bias,
    float* __restrict__ outp){
  int b = blockIdx.x & 15;
  int inner = (blockIdx.x >> 4)*256 + threadIdx.x;   // 0..196607
  int o = inner % 192; int n = inner / 192;
  int bn = (b << 10) + n;
  const float4* ip = (const float4*)(in + (size_t)bn*64);
  const float4* wp = (const float4*)(Wm + (size_t)o*64);
  float s = bias[o];
  #pragma unroll
  for (int c = 0; c < 16; ++c){
    float4 a = ip[c], wv = wp[c];
    s = fmaf(a.x, wv.x, s); s = fmaf(a.y, wv.y, s);
    s = fmaf(a.z, wv.z, s); s = fmaf(a.w, wv.w, s);
  }
  outp[(size_t)bn*192 + o] = s;
}

// ------- flash-decode attention (no-max exp): 2 heads/block ---------------------------
__global__ __launch_bounds__(256, 1) void k_attn_part(const float* __restrict__ qkv,
    float* __restrict__ pl, float* __restrict__ pacc){
  __shared__ __align__(16) float Ks[2][KPS*8];
  __shared__ __align__(16) float Vs[2][KPS*8];
  int blk = blockIdx.x;                // b(16, low bits) x ksl(8) x hp(4) = 512 blocks
  int b = blk & 15; int ksl = (blk >> 4) & 7; int hp = blk >> 7;
  int t = threadIdx.x;
  int hh = t >> 7;                     // wave-uniform head select within pair
  int h = hp*2 + hh;
  int lq = t & 127;
  for (int i = t; i < 2*KPS*8; i += 256){
    int hi = (i >= KPS*8) ? 1 : 0;
    int r = i - hi*KPS*8;
    int m = r >> 3, dd = r & 7;
    size_t base = ((size_t)b*ND + ksl*KPS + m)*192 + (hp*2 + hi)*8 + dd;
    Ks[hi][r] = qkv[base + 64];
    Vs[hi][r] = qkv[base + 128];
  }
  __syncthreads();
  const float scale = 0.35355339059327373f;
  float q[8][8];
  #pragma unroll
  for (int u = 0; u < 8; ++u){
    int n = u*128 + lq;
    const float4* qp = (const float4*)(qkv + ((size_t)b*ND + n)*192 + h*8);
    float4 q0 = qp[0], q1 = qp[1];
    q[u][0]=q0.x*scale; q[u][1]=q0.y*scale; q[u][2]=q0.z*scale; q[u][3]=q0.w*scale;
    q[u][4]=q1.x*scale; q[u][5]=q1.y*scale; q[u][6]=q1.z*scale; q[u][7]=q1.w*scale;
  }
  float l[8] = {};
  float acc[8][8] = {};
  for (int m = 0; m < KPS; ++m){
    float4 k0 = *(const float4*)&Ks[hh][m*8];
    float4 k1 = *(const float4*)&Ks[hh][m*8+4];
    float4 v0 = *(const float4*)&Vs[hh][m*8];
    float4 v1 = *(const float4*)&Vs[hh][m*8+4];
    #pragma unroll
    for (int u = 0; u < 8; ++u){
      float s;
      s = q[u][0]*k0.x;           s = fmaf(q[u][1], k0.y, s);
      s = fmaf(q[u][2], k0.z, s); s = fmaf(q[u][3], k0.w, s);
      s = fmaf(q[u][4], k1.x, s); s = fmaf(q[u][5], k1.y, s);
      s = fmaf(q[u][6], k1.z, s); s = fmaf(q[u][7], k1.w, s);
      float p = __expf(s);        // scores tiny: exp-without-max is safe; merge = sum
      l[u] += p;
      acc[u][0] = fmaf(p, v0.x, acc[u][0]);
      acc[u][1] = fmaf(p, v0.y, acc[u][1]);
      acc[u][2] = fmaf(p, v0.z, acc[u][2]);
      acc[u][3] = fmaf(p, v0.w, acc[u][3]);
      acc[u][4] = fmaf(p, v1.x, acc[u][4]);
      acc[u][5] = fmaf(p, v1.y, acc[u][5]);
      acc[u][6] = fmaf(p, v1.z, acc[u][6]);
      acc[u][7] = fmaf(p, v1.w, acc[u][7]);
    }
  }
  #pragma unroll
  for (int u = 0; u < 8; ++u){
    int n = u*128 + lq;
    size_t pidx = (((size_t)(b*8 + h))*8 + ksl)*ND + n;
    pl[pidx] = l[u];
    float4* ap = (float4*)&pacc[pidx*8];
    ap[0] = make_float4(acc[u][0], acc[u][1], acc[u][2], acc[u][3]);
    ap[1] = make_float4(acc[u][4], acc[u][5], acc[u][6], acc[u][7]);
  }
}

// ------- flash-decode combine: plain sums --------------------------------------------
__global__ __launch_bounds__(256) void k_attn_comb(const float* __restrict__ pl,
    const float* __restrict__ pacc, float* __restrict__ attno){
  int b = blockIdx.x & 15;
  int inner = (blockIdx.x >> 4)*256 + threadIdx.x;   // 0..8191 = h(8) x n(1024)
  int h = inner >> 10; int n = inner & 1023;
  int bh = b*8 + h;
  float L = 0.f;
  float o[8] = {};
  #pragma unroll
  for (int s = 0; s < KSL; ++s){
    size_t pidx = ((size_t)bh*8 + s)*ND + n;
    L += pl[pidx];
    const float4* ap = (const float4*)&pacc[pidx*8];
    float4 a0 = ap[0], a1 = ap[1];
    o[0] += a0.x; o[1] += a0.y; o[2] += a0.z; o[3] += a0.w;
    o[4] += a1.x; o[5] += a1.y; o[6] += a1.z; o[7] += a1.w;
  }
  float inv = 1.f/L;
  float4* dst = (float4*)&attno[((size_t)b*ND + n)*64 + h*8];
  dst[0] = make_float4(o[0]*inv, o[1]*inv, o[2]*inv, o[3]*inv);
  dst[1] = make_float4(o[4]*inv, o[5]*inv, o[6]*inv, o[7]*inv);
}

// ------- out-proj + pair-mean: emb[bn,f] = 0.5*(proj[2f]+proj[2f+1]) -----------------
__global__ __launch_bounds__(256) void k_projmean(const float* __restrict__ attno,
    const float* __restrict__ Wo, const float* __restrict__ bo,
    float* __restrict__ emb){
  int b = blockIdx.x & 15;
  int inner = (blockIdx.x >> 4)*256 + threadIdx.x;   // 0..32767 = n(1024) x f(32)
  int n = inner >> 5; int f = inner & 31;
  int bn = (b << 10) + n;
  const float4* ip = (const float4*)(attno + (size_t)bn*64);
  int o0 = 2*f, o1 = 2*f + 1;
  const float4* w0 = (const float4*)(Wo + (size_t)o0*64);
  const float4* w1 = (const float4*)(Wo + (size_t)o1*64);
  float s0 = bo[o0], s1 = bo[o1];
  #pragma unroll
  for (int c = 0; c < 16; ++c){
    float4 a = ip[c], u = w0[c], v = w1[c];
    s0 = fmaf(a.x,u.x,s0); s0 = fmaf(a.y,u.y,s0); s0 = fmaf(a.z,u.z,s0); s0 = fmaf(a.w,u.w,s0);
    s1 = fmaf(a.x,v.x,s1); s1 = fmaf(a.y,v.y,s1); s1 = fmaf(a.z,v.z,s1); s1 = fmaf(a.w,v.w,s1);
  }
  emb[(size_t)bn*32 + f] = 0.5f*(s0 + s1);
}

// ---------------- fused attention pool: one block per b16 ----------------------------
// sout base = out+8; b16*ND+n == br*(8*ND)+b8*ND+n (branch output slices contiguous)
__global__ __launch_bounds__(256) void k_poolfuse(const float* __restrict__ emb,
    const float* __restrict__ attw, float* __restrict__ sout,
    float* __restrict__ pooled){
  __shared__ float part[8][32];
  __shared__ float meanv[32];
  __shared__ float gv[32];
  __shared__ float sc[ND];
  int b = blockIdx.x, t = threadIdx.x;
  int f = t & 31, j = t >> 5;
  const float* eb = emb + (size_t)b*ND*32;
  float s = 0.f;
  for (int n = j; n < ND; n += 8) s += eb[n*32 + f];
  part[j][f] = s;
  __syncthreads();
  if (t < 32){
    float m = 0.f;
    for (int j2 = 0; j2 < 8; ++j2) m += part[j2][t];
    meanv[t] = m * (1.f/ND);
  }
  __syncthreads();
  if (t < 32){
    float acc = 0.f;
    for (int f2 = 0; f2 < 32; ++f2) acc = fmaf(meanv[f2], attw[f2*32 + t], acc);
    gv[t] = tanhf(acc);
  }
  __syncthreads();
  for (int n = t; n < ND; n += 256){
    const float4* ep = (const float4*)(eb + n*32);
    float acc = 0.f;
    #pragma unroll
    for (int f4 = 0; f4 < 8; ++f4){
      float4 e = ep[f4];
      acc = fmaf(e.x, gv[f4*4+0], acc);
      acc = fmaf(e.y, gv[f4*4+1], acc);
      acc = fmaf(e.z, gv[f4*4+2], acc);
      acc = fmaf(e.w, gv[f4*4+3], acc);
    }
    float sg = 1.f/(1.f + __expf(-acc));
    sout[(size_t)b*ND + n] = sg;
    sc[n] = sg;
  }
  __syncthreads();
  float pacc = 0.f;
  for (int n = j; n < ND; n += 8) pacc = fmaf(eb[n*32 + f], sc[n], pacc);
  part[j][f] = pacc;
  __syncthreads();
  if (t < 32){
    float m = 0.f;
    for (int j2 = 0; j2 < 8; ++j2) m += part[j2][t];
    pooled[b*32 + t] = m;
  }
}

// ---------------- NTN head: LDS-staged weights (2-phase, 32KB each) ------------------
__global__ __launch_bounds__(256) void k_head(const float* __restrict__ p1,
    const float* __restrict__ p2, const float* __restrict__ ntnw,
    const float* __restrict__ ntnv, const float* __restrict__ ntnb,
    const float* __restrict__ fc1w, const float* __restrict__ fc1b,
    const float* __restrict__ scw, const float* __restrict__ scb,
    float* __restrict__ outscore){
  __shared__ __align__(16) float Wl[8192];
  __shared__ float Vl[512];
  __shared__ float F1[256];
  __shared__ float ds[8][32];
  __shared__ float tv[8][16];
  __shared__ float hv[8][16];
  int t = threadIdx.x;
  {
    int b = t >> 5, f = t & 31;
    ds[b][f] = p1[b*32+f] - p2[b*32+f];
  }
  for (int i = t; i < 512; i += 256) Vl[i] = ntnv[i];
  if (t < 256) F1[t] = fc1w[t];
  float acc = 0.f;
  for (int ph = 0; ph < 2; ++ph){
    __syncthreads();
    {
      const float4* src = (const float4*)(ntnw + ph*8192);
      float4* dst = (float4*)Wl;
      for (int i = t; i < 2048; i += 256) dst[i] = src[i];
    }
    __syncthreads();
    if (t < 128){
      int b = t >> 4, tt = t & 15;
      for (int fi = 0; fi < 16; ++fi){
        float df = ds[b][ph*16 + fi];
        #pragma unroll 8
        for (int gg = 0; gg < 32; ++gg)
          acc = fmaf(df*ds[b][gg], Wl[(fi*32+gg)*16 + tt], acc);
      }
    }
  }
  if (t < 128){
    int b = t >> 4, tt = t & 15;
    acc += ntnb[tt];
    for (int gg = 0; gg < 32; ++gg) acc = fmaf(ds[b][gg], Vl[tt*32+gg], acc);
    tv[b][tt] = fmaxf(acc, 0.f);
  }
  __syncthreads();
  if (t < 128){
    int b = t >> 4, i = t & 15;
    float a2 = fc1b[i];
    for (int kk = 0; kk < 16; ++kk) a2 = fmaf(tv[b][kk], F1[i*16+kk], a2);
    hv[b][i] = fmaxf(a2, 0.f);
  }
  __syncthreads();
  if (t < 8){
    float a3 = scb[0];
    for (int i = 0; i < 16; ++i) a3 = fmaf(hv[t][i], scw[i], a3);
    outscore[t] = 1.f/(1.f + __expf(-a3));
  }
}

// =====================================================================================
extern "C" void kernel_launch(void* const* d_in, const int* in_sizes, int n_in,
                              void* d_out, int out_size, void* d_ws, size_t ws_size,
                              hipStream_t stream) {
  auto F = [&](int i){ return (const float*)d_in[i]; };
  const float* f1 = F(0); const float* f2 = F(1);
  const float* cw[3] = { F(2), F(6), F(10) };
  const float* cb[3] = { F(3), F(7), F(11) };
  const float* cg[3] = { F(4), F(8), F(12) };
  const float* cB[3] = { F(5), F(9), F(13) };
  const float* sw[3] = { F(14), F(18), F(22) };
  const float* sb[3] = { F(15), F(19), F(23) };
  const float* sg[3] = { F(16), F(20), F(24) };
  const float* sB[3] = { F(17), F(21), F(25) };
  const float* mha_wi = F(26); const float* mha_bi = F(27);
  const float* mha_wo = F(28); const float* mha_bo = F(29);
  const float* att_w  = F(30);
  const float* ntn_w  = F(31); const float* ntn_v = F(32); const float* ntn_b = F(33);
  const float* fc1_w  = F(34); const float* fc1_b = F(35);
  const float* sc_w   = F(36); const float* sc_b  = F(37);
  float* out = (float*)d_out;

  char* ws = (char*)d_ws;
  const size_t MB = 1 << 20;
  // Edge-conv segment [0, 35MB) -- dead before the MHA phase begins:
  float* xA   = (float*)(ws + 0*MB);        // 8 MB  (16 x 1024 x 128 x 4)
  float* xB   = (float*)(ws + 8*MB);        // 8 MB
  float* zs   = (float*)(ws + 16*MB);       // 8 MB
  float* cvb  = (float*)(ws + 24*MB);       // 8 MB
  int*   idxb = (int*)  (ws + 32*MB);       // 1.25 MB
  float* xxb  = (float*)(ws + 34*MB);       // 64 KB
  float* fuse = (float*)(ws + 35*MB);       // 4 MB  [dies after k_lin]
  // MHA segment aliases the dead edge-conv buffers (stream-sequential, safe):
  float* qkv   = (float*)(ws + 0*MB);       // 12 MB over xA + xB-low   (dead)
  float* plb   = (float*)(ws + 12*MB);      // 4 MB  over xB-high       (dead)
  float* paccb = (float*)(ws + 16*MB);      // 32 MB over zs,cvb,idx,xx,fuse (dead)
  float* attno = (float*)(ws + 48*MB);      // 4 MB fresh
  float* emb   = (float*)(ws + 52*MB);      // 2 MB fresh
  float* pooled= (float*)(ws + 54*MB);      // 2 KB
  (void)ws_size;

  auto knn = [&](const float* xin, int CS, int nch8){
    k_knn<<<BD*64, 256, 0, stream>>>(xin, xxb, idxb, CS, nch8);
  };
  auto phA = [&](const float* xin, int C, int XS, int O, const float* W, const float* bb,
                 const float* gg, const float* be){
    if (O == 64)       k_phaseA<64> <<<BD*32, 256, 0, stream>>>(xin, W, bb, gg, be, zs, cvb, C, XS);
    else if (O == 128) k_phaseA<128><<<BD*32, 256, 0, stream>>>(xin, W, bb, gg, be, zs, cvb, C, XS);
    else               k_phaseA<32> <<<BD*32, 256, 0, stream>>>(xin, W, bb, gg, be, zs, cvb, C, XS);
  };

  for (int part = 0; part < 2; ++part){
    const float* const* Wl = part ? sw : cw;
    const float* const* bl = part ? sb : cb;
    const float* const* gl = part ? sg : cg;
    const float* const* Bl = part ? sB : cB;
    int C0 = part ? 12 : 3;
    int CS0 = part ? 12 : 4;
    // layer 0: C0 -> 64 (both branches at once: 16 batches)
    if (part) k_prep<12,12><<<BD*ND/256, 256, 0, stream>>>(f1, f2, xA, xxb, 3);
    else      k_prep<3, 4> <<<BD*ND/256, 256, 0, stream>>>(f1, f2, xA, xxb, 0);
    knn(xA, CS0, part ? 2 : 1);
    phA(xA, C0, CS0, 64, Wl[0], bl[0], gl[0], Bl[0]);
    k_phaseB<true,true><<<BD*ND/4, 256, 0, stream>>>(zs, cvb, idxb, xB, xxb, 64, 0, 0);
    // layer 1: 64 -> 128 (xx produced by phaseB)
    knn(xB, 64, 8);
    phA(xB, 64, 64, 128, Wl[1], bl[1], gl[1], Bl[1]);
    k_phaseB<true,true><<<BD*ND/4, 256, 0, stream>>>(zs, cvb, idxb, xA, xxb, 128, 0, 0);
    // layer 2: 128 -> 32, written into fuse at column offset (row-major)
    knn(xA, 128, 16);
    phA(xA, 128, 128, 32, Wl[2], bl[2], gl[2], Bl[2]);
    k_phaseB<false,false><<<BD*ND/4, 256, 0, stream>>>(zs, cvb, idxb, fuse, nullptr, 32, 64, part*32);
  }
  // MHA (flash-decode, no-max exp) over all 16 batches
  k_lin<<<(BD*ND*192)/256, 256, 0, stream>>>(fuse, mha_wi, mha_bi, qkv);
  k_attn_part<<<BD*4*KSL, 256, 0, stream>>>(qkv, plb, paccb);
  k_attn_comb<<<(BD*8*ND)/256, 256, 0, stream>>>(plb, paccb, attno);
  k_projmean<<<(BD*ND*32)/256, 256, 0, stream>>>(attno, mha_wo, mha_bo, emb);
  // fused attention pool (sout slices are contiguous across the 16 batches)
  k_poolfuse<<<BD, 256, 0, stream>>>(emb, att_w, out + 8, pooled);
  k_head<<<1, 256, 0, stream>>>(pooled, pooled + 256, ntn_w, ntn_v, ntn_b,
                                fc1_w, fc1_b, sc_w, sc_b, out);
}

// Round 13
// 996.115 us; speedup vs baseline: 2.0917x; 1.1069x over previous
//
#include <hip/hip_runtime.h>
#include <math.h>

#define BD 16      // fused batches: 2 branches x 8
#define ND 1024
#define KNN 20
#define NEGS 0.2f
#define BNSC 0.99999500003749969482f
#define KSL 8      // key slices for flash-decode attention
#define KPS 128    // keys per slice

__device__ __forceinline__ float leakyf(float y){ return y >= 0.f ? y : NEGS*y; }

// async global->LDS DMA, 16B per lane: dest = wave-uniform base + lane*16 (HW rule),
// src = per-lane. With the tiled x layout the src is lane-CONTIGUOUS (1KB/instr).
__device__ __forceinline__ void gl_lds16(const float* g, float* l){
  __builtin_amdgcn_global_load_lds(
      (const __attribute__((address_space(1))) void*)g,
      (__attribute__((address_space(3))) void*)l, 16, 0, 0);
}

// r13: k_lin rewritten as an LDS-tiled GEMM. r12 counters showed k_lin at 114.7us,
// VALUBusy 5.5%: each thread's private weight row = 256B-stride scatter (64 lines/
// wave-instr) on a 48KB matrix that misses the 32KB L1 -> L2-latency-bound. Fix =
// stage W once per block (coalesced) into transposed LDS, 32 rows x 192 outs per
// block, phaseA-style register blocking. acc inits to bias -> bitwise-identical.

// -------- fused input slice + transpose + xx: tiled write, both branches -------------
template<int C, int CS>
__global__ __launch_bounds__(256) void k_prep(const float* __restrict__ f1,
                                              const float* __restrict__ f2,
                                              float* __restrict__ x,
                                              float* __restrict__ xx, int c0){
  int blk = blockIdx.x;
  int b = blk & 15;
  int n = (blk >> 4)*256 + threadIdx.x;
  const float* feat = (b & 8) ? f2 : f1;
  int b8 = b & 7;
  float v[CS];
  float s = 0.f;
  #pragma unroll
  for (int c = 0; c < C; ++c){
    v[c] = feat[((size_t)(b8*15) + c0 + c)*ND + n];
    s = fmaf(v[c], v[c], s);
  }
  #pragma unroll
  for (int c = C; c < CS; ++c) v[c] = 0.f;
  #pragma unroll
  for (int g = 0; g < CS/4; ++g)
    *(float4*)&x[(size_t)(b*CS + g*4)*ND + (size_t)n*4] =
        make_float4(v[g*4], v[g*4+1], v[g*4+2], v[g*4+3]);
  xx[b*ND + n] = s;
}

// -------- fused gram + exact top-20: DMA ping-pong staging (r12 proven) --------------
__global__ __launch_bounds__(256)
void k_knn(const float* __restrict__ x,
    const float* __restrict__ xx, int* __restrict__ idxp, int CS, int nchunk){
  __shared__ __align__(16) float Xc[2][2][4096];   // [buf][quad-array][1024*4] = 64KB
  int b = blockIdx.x & 15;
  int r0 = (blockIdx.x >> 4)*16;
  int t = threadIdx.x;
  int lane = t & 63;
  int w = __builtin_amdgcn_readfirstlane(t >> 6);   // wave-uniform wave id
  const float* xb = x + (size_t)b*ND*CS;            // tiled [G][n][4]
  float acc[4][16];
  #pragma unroll
  for (int j = 0; j < 4; ++j)
    #pragma unroll
    for (int q = 0; q < 16; ++q) acc[j][q] = 0.f;

  // stage chunk ch (quads 2ch, 2ch+1) into buffer buf via DMA; zero-fill padded quads
  auto stage = [&](int buf, int ch){
    int g0 = 2*ch, g1 = 2*ch + 1;
    bool v1 = (g1*4 < CS);                       // g0 always valid by construction
    #pragma unroll
    for (int i = 0; i < 4; ++i){
      int m = i*256 + t;
      unsigned ub = (unsigned)((i*256 + (w << 6))*4);   // wave-uniform elem base
      gl_lds16(&xb[((size_t)g0*ND + m)*4], &Xc[buf][0][ub]);
      if (v1) gl_lds16(&xb[((size_t)g1*ND + m)*4], &Xc[buf][1][ub]);
      else    *(float4*)&Xc[buf][1][m*4] = make_float4(0.f,0.f,0.f,0.f);
    }
  };

  stage(0, 0);
  __syncthreads();              // drains vmcnt: buffer 0 ready
  int cur = 0;
  for (int ch = 0; ch < nchunk; ++ch){
    bool more = (ch + 1 < nchunk);
    if (more) stage(cur ^ 1, ch + 1);   // DMA in flight during the FMA phase
    // row fragments from LDS (rows r0..r0+15 are columns; uniform-addr broadcast)
    float4 rv0[4], rv1[4];
    #pragma unroll
    for (int j = 0; j < 4; ++j){
      rv0[j] = *(const float4*)&Xc[cur][0][(r0 + w*4 + j)*4];
      rv1[j] = *(const float4*)&Xc[cur][1][(r0 + w*4 + j)*4];
    }
    #pragma unroll
    for (int q = 0; q < 16; ++q){
      float4 cv0 = *(const float4*)&Xc[cur][0][(q*64 + lane)*4];
      float4 cv1 = *(const float4*)&Xc[cur][1][(q*64 + lane)*4];
      #pragma unroll
      for (int j = 0; j < 4; ++j){
        float s = acc[j][q];   // strict sequential col order: bitwise-stable result
        s = fmaf(rv0[j].x, cv0.x, s); s = fmaf(rv0[j].y, cv0.y, s);
        s = fmaf(rv0[j].z, cv0.z, s); s = fmaf(rv0[j].w, cv0.w, s);
        s = fmaf(rv1[j].x, cv1.x, s); s = fmaf(rv1[j].y, cv1.y, s);
        s = fmaf(rv1[j].z, cv1.z, s); s = fmaf(rv1[j].w, cv1.w, s);
        acc[j][q] = s;
      }
    }
    if (more){
      __syncthreads();   // all waves done reading cur; my ch+1 DMA drained (had
      cur ^= 1;          // the full FMA phase to land) -> idle buf ready
    }
  }
  // transform to negdist = 2*dot - xx_r - xx_m, then to sortable uints
  float xxm[16];
  #pragma unroll
  for (int q = 0; q < 16; ++q) xxm[q] = xx[b*ND + q*64 + lane];
  unsigned uk[4][16];
  #pragma unroll
  for (int j = 0; j < 4; ++j){
    float xr = xx[b*ND + r0 + w*4 + j];
    #pragma unroll
    for (int q = 0; q < 16; ++q){
      float f = 2.f*acc[j][q] - xr - xxm[q];
      unsigned bv = __float_as_uint(f);
      uk[j][q] = (bv & 0x80000000u) ? ~bv : (bv | 0x80000000u);  // order-preserving
    }
  }
  // radix binary search for T = 20th-largest key per row (bit 31: only the diagonal
  // reaches it, count==1<20 always -> skip). Early exit at exact count==20 (set-equal).
  unsigned pref[4] = {0u, 0u, 0u, 0u};
  unsigned done = 0u;
  #pragma unroll 1
  for (int bit = 30; bit >= 0; --bit){
    #pragma unroll
    for (int u = 0; u < 4; ++u){
      if (done & (1u << u)) continue;           // wave-uniform (ballot-derived)
      unsigned cand = pref[u] | (1u << bit);
      int c = 0;
      #pragma unroll
      for (int q = 0; q < 16; ++q)
        c += (int)__popcll(__ballot(uk[u][q] >= cand));
      if (c >= KNN){
        pref[u] = cand;
        if (c == KNN) done |= (1u << u);
      }
    }
    if (done == 15u) break;
  }
  // emit: all keys > T, plus lowest-global-index keys == T to fill to 20
  unsigned long long mlt = (1ull << lane) - 1ull;   // lanes below me
  #pragma unroll
  for (int u = 0; u < 4; ++u){
    unsigned T = pref[u];
    int cg = 0;
    #pragma unroll
    for (int q = 0; q < 16; ++q) cg += (int)__popcll(__ballot(uk[u][q] > T));
    int need_eq = KNN - cg;                          // >= 1 by construction
    int* op = &idxp[((size_t)(b*ND + r0 + w*4 + u))*KNN];
    int run_gt = 0, run_eq = 0;
    #pragma unroll
    for (int q = 0; q < 16; ++q){
      unsigned k = uk[u][q];
      unsigned long long bg = __ballot(k > T);
      unsigned long long be = __ballot(k == T);
      if (k > T) op[run_gt + (int)__popcll(bg & mlt)] = q*64 + lane;
      if (k == T){
        int r = run_eq + (int)__popcll(be & mlt);
        if (r < need_eq) op[cg + r] = q*64 + lane;
      }
      run_gt += (int)__popcll(bg);
      run_eq += (int)__popcll(be);
    }
  }
}

// ------ phase A (register-blocked), tiled x, 16 batches (grid 512 = 2 blocks/CU) -----
template<int O>
__global__ __launch_bounds__(256) void k_phaseA(const float* __restrict__ x,
    const float* __restrict__ W, const float* __restrict__ bias,
    const float* __restrict__ gamma, const float* __restrict__ beta,
    float* __restrict__ zs, float* __restrict__ ccv, int C, int XS){
  constexpr int TO = O/16;
  constexpr int WP = O + 4;
  __shared__ float W1s[32*WP];
  __shared__ float dWs[32*WP];
  __shared__ float Xs[32*33];
  int blk = blockIdx.x;
  int b = blk & 15, n0 = (blk >> 4)*32;
  int t = threadIdx.x;
  int ot = t & 15, nt = t >> 4;
  int obase = ot*TO;
  int nl = nt*2;
  float az[TO][2] = {}, ac[TO][2] = {};
  for (int cc = 0; cc < C; cc += 32){
    int KC = (C - cc < 32) ? (C - cc) : 32;
    int NG = (KC + 3) >> 2;
    for (int i = t; i < O*KC; i += 256){
      int o = i % O, c = i / O;
      float w1 = W[(size_t)o*2*C + cc + c];
      float w2 = W[(size_t)o*2*C + C + cc + c];
      W1s[c*WP + o] = w1;
      dWs[c*WP + o] = w2 - w1;
    }
    for (int i = t; i < 32*NG; i += 256){
      int row = i & 31, g = i >> 5;
      float4 v = *(const float4*)&x[(size_t)(b*XS + cc + g*4)*ND + (size_t)(n0+row)*4];
      Xs[(g*4+0)*33 + row] = v.x;
      Xs[(g*4+1)*33 + row] = v.y;
      Xs[(g*4+2)*33 + row] = v.z;
      Xs[(g*4+3)*33 + row] = v.w;
    }
    __syncthreads();
    for (int c = 0; c < KC; ++c){
      float xv0 = Xs[c*33 + nl];
      float xv1 = Xs[c*33 + nl + 1];
      #pragma unroll
      for (int i = 0; i < TO; ++i){
        float w1 = W1s[c*WP + obase + i];
        float dw = dWs[c*WP + obase + i];
        az[i][0] = fmaf(w1, xv0, az[i][0]);
        az[i][1] = fmaf(w1, xv1, az[i][1]);
        ac[i][0] = fmaf(dw, xv0, ac[i][0]);
        ac[i][1] = fmaf(dw, xv1, ac[i][1]);
      }
    }
    __syncthreads();
  }
  #pragma unroll
  for (int i = 0; i < TO; ++i){
    int o = obase + i;
    float alpha = gamma[o]*BNSC;
    float bb = bias[o], be = beta[o];
    #pragma unroll
    for (int q = 0; q < 2; ++q){
      int n = n0 + nl + q;
      size_t off = ((size_t)b*ND + n)*O + o;
      zs[off]  = az[i][q]*alpha;
      ccv[off] = fmaf(ac[i][q] + bb, alpha, be);
    }
  }
}

// ------ phase B: out = max_k leaky(zs[idx_k]+cc); TILED knn-layout writes ------------
template<bool DOXX, bool TILED>
__global__ __launch_bounds__(256) void k_phaseB(const float* __restrict__ zs,
    const float* __restrict__ ccv, const int* __restrict__ idxp,
    float* __restrict__ outp, float* __restrict__ xxout,
    int O, int ostride, int ooff){
  int t = threadIdx.x;
  int lane = t & 63, w = t >> 6;
  int b = blockIdx.x & 15;
  int n = (blockIdx.x >> 4)*4 + w;
  int gn = (b << 10) + n;
  int mm[KNN];
  const int* ip = idxp + (size_t)gn*KNN;
  #pragma unroll
  for (int k = 0; k < KNN; ++k) mm[k] = ip[k];
  float sq = 0.f;
  for (int o = lane; o < O; o += 64){
    float cvv = ccv[(size_t)gn*O + o];
    float mx = -INFINITY;
    #pragma unroll 4
    for (int k = 0; k < KNN; ++k){
      float v = leakyf(zs[((size_t)(b*ND) + mm[k])*O + o] + cvv);
      mx = fmaxf(mx, v);
    }
    if (TILED)
      outp[(size_t)(b*O + (o & ~3))*ND + (size_t)n*4 + (o & 3)] = mx;
    else
      outp[(size_t)gn*ostride + ooff + o] = mx;
    if (DOXX) sq = fmaf(mx, mx, sq);
  }
  if (DOXX){
    #pragma unroll
    for (int off = 32; off; off >>= 1) sq += __shfl_down(sq, off);
    if (lane == 0) xxout[gn] = sq;
  }
}

// --------- qkv: LDS-tiled GEMM [16K x 64] @ [64 x 192] + bias ------------------------
// 512 blocks (b-affinity), 32 rows x 192 outs per block. W staged once per block
// (coalesced global read) into transposed LDS Ws[c][o] (pad 196: <=2-way bank alias,
// free). Thread = 12 outputs x 2 rows; acc inits to bias, c ascending -> bitwise
// identical to the naive version. Replaces the 256B-stride weight scatter that was
// L2-latency-bound (114.7us, VALUBusy 5.5% in r12).
__global__ __launch_bounds__(256) void k_lin(const float* __restrict__ in,
    const float* __restrict__ Wm, const float* __restrict__ bias,
    float* __restrict__ outp){
  __shared__ float Ws[64*196];    // 50.2 KB: Ws[c*196 + o]
  __shared__ float Xs[64*33];     // 8.4 KB:  Xs[c*33 + row]
  int blk = blockIdx.x;
  int b = blk & 15, n0 = (blk >> 4)*32;
  int bn0 = (b << 10) + n0;
  int t = threadIdx.x;
  int ot = t & 15, nt = t >> 4;
  int obase = ot*12;
  int nl = nt*2;
  // stage W transposed: coalesced global read Wm[o*64+c] (i contiguous)
  for (int i = t; i < 192*64; i += 256){
    int c = i & 63, o = i >> 6;
    Ws[c*196 + o] = Wm[i];
  }
  // stage A-tile: coalesced float4 rows -> Xs[c][row]
  for (int i = t; i < 32*16; i += 256){
    int row = i >> 4, c4 = i & 15;
    float4 v = *(const float4*)&in[((size_t)(bn0 + row))*64 + c4*4];
    Xs[(c4*4+0)*33 + row] = v.x;
    Xs[(c4*4+1)*33 + row] = v.y;
    Xs[(c4*4+2)*33 + row] = v.z;
    Xs[(c4*4+3)*33 + row] = v.w;
  }
  __syncthreads();
  float acc[12][2];
  #pragma unroll
  for (int i = 0; i < 12; ++i){
    float bb = bias[obase + i];
    acc[i][0] = bb; acc[i][1] = bb;     // bias first, then c ascending == old order
  }
  for (int c = 0; c < 64; ++c){
    float xv0 = Xs[c*33 + nl];
    float xv1 = Xs[c*33 + nl + 1];
    #pragma unroll
    for (int i = 0; i < 12; ++i){
      float wv = Ws[c*196 + obase + i];
      acc[i][0] = fmaf(wv, xv0, acc[i][0]);
      acc[i][1] = fmaf(wv, xv1, acc[i][1]);
    }
  }
  #pragma unroll
  for (int q = 0; q < 2; ++q){
    float* op = &outp[(size_t)(bn0 + nl + q)*192 + obase];
    #pragma unroll
    for (int v4 = 0; v4 < 3; ++v4)
      *(float4*)&op[v4*4] = make_float4(acc[v4*4+0][q], acc[v4*4+1][q],
                                        acc[v4*4+2][q], acc[v4*4+3][q]);
  }
}

// ------- flash-decode attention (no-max exp): 2 heads/block ---------------------------
__global__ __launch_bounds__(256, 1) void k_attn_part(const float* __restrict__ qkv,
    float* __restrict__ pl, float* __restrict__ pacc){
  __shared__ __align__(16) float Ks[2][KPS*8];
  __shared__ __align__(16) float Vs[2][KPS*8];
  int blk = blockIdx.x;                // b(16, low bits) x ksl(8) x hp(4) = 512 blocks
  int b = blk & 15; int ksl = (blk >> 4) & 7; int hp = blk >> 7;
  int t = threadIdx.x;
  int hh = t >> 7;                     // wave-uniform head select within pair
  int h = hp*2 + hh;
  int lq = t & 127;
  for (int i = t; i < 2*KPS*8; i += 256){
    int hi = (i >= KPS*8) ? 1 : 0;
    int r = i - hi*KPS*8;
    int m = r >> 3, dd = r & 7;
    size_t base = ((size_t)b*ND + ksl*KPS + m)*192 + (hp*2 + hi)*8 + dd;
    Ks[hi][r] = qkv[base + 64];
    Vs[hi][r] = qkv[base + 128];
  }
  __syncthreads();
  const float scale = 0.35355339059327373f;
  float q[8][8];
  #pragma unroll
  for (int u = 0; u < 8; ++u){
    int n = u*128 + lq;
    const float4* qp = (const float4*)(qkv + ((size_t)b*ND + n)*192 + h*8);
    float4 q0 = qp[0], q1 = qp[1];
    q[u][0]=q0.x*scale; q[u][1]=q0.y*scale; q[u][2]=q0.z*scale; q[u][3]=q0.w*scale;
    q[u][4]=q1.x*scale; q[u][5]=q1.y*scale; q[u][6]=q1.z*scale; q[u][7]=q1.w*scale;
  }
  float l[8] = {};
  float acc[8][8] = {};
  for (int m = 0; m < KPS; ++m){
    float4 k0 = *(const float4*)&Ks[hh][m*8];
    float4 k1 = *(const float4*)&Ks[hh][m*8+4];
    float4 v0 = *(const float4*)&Vs[hh][m*8];
    float4 v1 = *(const float4*)&Vs[hh][m*8+4];
    #pragma unroll
    for (int u = 0; u < 8; ++u){
      float s;
      s = q[u][0]*k0.x;           s = fmaf(q[u][1], k0.y, s);
      s = fmaf(q[u][2], k0.z, s); s = fmaf(q[u][3], k0.w, s);
      s = fmaf(q[u][4], k1.x, s); s = fmaf(q[u][5], k1.y, s);
      s = fmaf(q[u][6], k1.z, s); s = fmaf(q[u][7], k1.w, s);
      float p = __expf(s);        // scores tiny: exp-without-max is safe; merge = sum
      l[u] += p;
      acc[u][0] = fmaf(p, v0.x, acc[u][0]);
      acc[u][1] = fmaf(p, v0.y, acc[u][1]);
      acc[u][2] = fmaf(p, v0.z, acc[u][2]);
      acc[u][3] = fmaf(p, v0.w, acc[u][3]);
      acc[u][4] = fmaf(p, v1.x, acc[u][4]);
      acc[u][5] = fmaf(p, v1.y, acc[u][5]);
      acc[u][6] = fmaf(p, v1.z, acc[u][6]);
      acc[u][7] = fmaf(p, v1.w, acc[u][7]);
    }
  }
  #pragma unroll
  for (int u = 0; u < 8; ++u){
    int n = u*128 + lq;
    size_t pidx = (((size_t)(b*8 + h))*8 + ksl)*ND + n;
    pl[pidx] = l[u];
    float4* ap = (float4*)&pacc[pidx*8];
    ap[0] = make_float4(acc[u][0], acc[u][1], acc[u][2], acc[u][3]);
    ap[1] = make_float4(acc[u][4], acc[u][5], acc[u][6], acc[u][7]);
  }
}

// ------- flash-decode combine: plain sums --------------------------------------------
__global__ __launch_bounds__(256) void k_attn_comb(const float* __restrict__ pl,
    const float* __restrict__ pacc, float* __restrict__ attno){
  int b = blockIdx.x & 15;
  int inner = (blockIdx.x >> 4)*256 + threadIdx.x;   // 0..8191 = h(8) x n(1024)
  int h = inner >> 10; int n = inner & 1023;
  int bh = b*8 + h;
  float L = 0.f;
  float o[8] = {};
  #pragma unroll
  for (int s = 0; s < KSL; ++s){
    size_t pidx = ((size_t)bh*8 + s)*ND + n;
    L += pl[pidx];
    const float4* ap = (const float4*)&pacc[pidx*8];
    float4 a0 = ap[0], a1 = ap[1];
    o[0] += a0.x; o[1] += a0.y; o[2] += a0.z; o[3] += a0.w;
    o[4] += a1.x; o[5] += a1.y; o[6] += a1.z; o[7] += a1.w;
  }
  float inv = 1.f/L;
  float4* dst = (float4*)&attno[((size_t)b*ND + n)*64 + h*8];
  dst[0] = make_float4(o[0]*inv, o[1]*inv, o[2]*inv, o[3]*inv);
  dst[1] = make_float4(o[4]*inv, o[5]*inv, o[6]*inv, o[7]*inv);
}

// ------- out-proj + pair-mean: emb[bn,f] = 0.5*(proj[2f]+proj[2f+1]) -----------------
__global__ __launch_bounds__(256) void k_projmean(const float* __restrict__ attno,
    const float* __restrict__ Wo, const float* __restrict__ bo,
    float* __restrict__ emb){
  int b = blockIdx.x & 15;
  int inner = (blockIdx.x >> 4)*256 + threadIdx.x;   // 0..32767 = n(1024) x f(32)
  int n = inner >> 5; int f = inner & 31;
  int bn = (b << 10) + n;
  const float4* ip = (const float4*)(attno + (size_t)bn*64);
  int o0 = 2*f, o1 = 2*f + 1;
  const float4* w0 = (const float4*)(Wo + (size_t)o0*64);
  const float4* w1 = (const float4*)(Wo + (size_t)o1*64);
  float s0 = bo[o0], s1 = bo[o1];
  #pragma unroll
  for (int c = 0; c < 16; ++c){
    float4 a = ip[c], u = w0[c], v = w1[c];
    s0 = fmaf(a.x,u.x,s0); s0 = fmaf(a.y,u.y,s0); s0 = fmaf(a.z,u.z,s0); s0 = fmaf(a.w,u.w,s0);
    s1 = fmaf(a.x,v.x,s1); s1 = fmaf(a.y,v.y,s1); s1 = fmaf(a.z,v.z,s1); s1 = fmaf(a.w,v.w,s1);
  }
  emb[(size_t)bn*32 + f] = 0.5f*(s0 + s1);
}

// ---------------- fused attention pool: one block per b16 ----------------------------
// sout base = out+8; b16*ND+n == br*(8*ND)+b8*ND+n (branch output slices contiguous)
__global__ __launch_bounds__(256) void k_poolfuse(const float* __restrict__ emb,
    const float* __restrict__ attw, float* __restrict__ sout,
    float* __restrict__ pooled){
  __shared__ float part[8][32];
  __shared__ float meanv[32];
  __shared__ float gv[32];
  __shared__ float sc[ND];
  int b = blockIdx.x, t = threadIdx.x;
  int f = t & 31, j = t >> 5;
  const float* eb = emb + (size_t)b*ND*32;
  float s = 0.f;
  for (int n = j; n < ND; n += 8) s += eb[n*32 + f];
  part[j][f] = s;
  __syncthreads();
  if (t < 32){
    float m = 0.f;
    for (int j2 = 0; j2 < 8; ++j2) m += part[j2][t];
    meanv[t] = m * (1.f/ND);
  }
  __syncthreads();
  if (t < 32){
    float acc = 0.f;
    for (int f2 = 0; f2 < 32; ++f2) acc = fmaf(meanv[f2], attw[f2*32 + t], acc);
    gv[t] = tanhf(acc);
  }
  __syncthreads();
  for (int n = t; n < ND; n += 256){
    const float4* ep = (const float4*)(eb + n*32);
    float acc = 0.f;
    #pragma unroll
    for (int f4 = 0; f4 < 8; ++f4){
      float4 e = ep[f4];
      acc = fmaf(e.x, gv[f4*4+0], acc);
      acc = fmaf(e.y, gv[f4*4+1], acc);
      acc = fmaf(e.z, gv[f4*4+2], acc);
      acc = fmaf(e.w, gv[f4*4+3], acc);
    }
    float sg = 1.f/(1.f + __expf(-acc));
    sout[(size_t)b*ND + n] = sg;
    sc[n] = sg;
  }
  __syncthreads();
  float pacc = 0.f;
  for (int n = j; n < ND; n += 8) pacc = fmaf(eb[n*32 + f], sc[n], pacc);
  part[j][f] = pacc;
  __syncthreads();
  if (t < 32){
    float m = 0.f;
    for (int j2 = 0; j2 < 8; ++j2) m += part[j2][t];
    pooled[b*32 + t] = m;
  }
}

// ---------------- NTN head: LDS-staged weights (2-phase, 32KB each) ------------------
__global__ __launch_bounds__(256) void k_head(const float* __restrict__ p1,
    const float* __restrict__ p2, const float* __restrict__ ntnw,
    const float* __restrict__ ntnv, const float* __restrict__ ntnb,
    const float* __restrict__ fc1w, const float* __restrict__ fc1b,
    const float* __restrict__ scw, const float* __restrict__ scb,
    float* __restrict__ outscore){
  __shared__ __align__(16) float Wl[8192];
  __shared__ float Vl[512];
  __shared__ float F1[256];
  __shared__ float ds[8][32];
  __shared__ float tv[8][16];
  __shared__ float hv[8][16];
  int t = threadIdx.x;
  {
    int b = t >> 5, f = t & 31;
    ds[b][f] = p1[b*32+f] - p2[b*32+f];
  }
  for (int i = t; i < 512; i += 256) Vl[i] = ntnv[i];
  if (t < 256) F1[t] = fc1w[t];
  float acc = 0.f;
  for (int ph = 0; ph < 2; ++ph){
    __syncthreads();
    {
      const float4* src = (const float4*)(ntnw + ph*8192);
      float4* dst = (float4*)Wl;
      for (int i = t; i < 2048; i += 256) dst[i] = src[i];
    }
    __syncthreads();
    if (t < 128){
      int b = t >> 4, tt = t & 15;
      for (int fi = 0; fi < 16; ++fi){
        float df = ds[b][ph*16 + fi];
        #pragma unroll 8
        for (int gg = 0; gg < 32; ++gg)
          acc = fmaf(df*ds[b][gg], Wl[(fi*32+gg)*16 + tt], acc);
      }
    }
  }
  if (t < 128){
    int b = t >> 4, tt = t & 15;
    acc += ntnb[tt];
    for (int gg = 0; gg < 32; ++gg) acc = fmaf(ds[b][gg], Vl[tt*32+gg], acc);
    tv[b][tt] = fmaxf(acc, 0.f);
  }
  __syncthreads();
  if (t < 128){
    int b = t >> 4, i = t & 15;
    float a2 = fc1b[i];
    for (int kk = 0; kk < 16; ++kk) a2 = fmaf(tv[b][kk], F1[i*16+kk], a2);
    hv[b][i] = fmaxf(a2, 0.f);
  }
  __syncthreads();
  if (t < 8){
    float a3 = scb[0];
    for (int i = 0; i < 16; ++i) a3 = fmaf(hv[t][i], scw[i], a3);
    outscore[t] = 1.f/(1.f + __expf(-a3));
  }
}

// =====================================================================================
extern "C" void kernel_launch(void* const* d_in, const int* in_sizes, int n_in,
                              void* d_out, int out_size, void* d_ws, size_t ws_size,
                              hipStream_t stream) {
  auto F = [&](int i){ return (const float*)d_in[i]; };
  const float* f1 = F(0); const float* f2 = F(1);
  const float* cw[3] = { F(2), F(6), F(10) };
  const float* cb[3] = { F(3), F(7), F(11) };
  const float* cg[3] = { F(4), F(8), F(12) };
  const float* cB[3] = { F(5), F(9), F(13) };
  const float* sw[3] = { F(14), F(18), F(22) };
  const float* sb[3] = { F(15), F(19), F(23) };
  const float* sg[3] = { F(16), F(20), F(24) };
  const float* sB[3] = { F(17), F(21), F(25) };
  const float* mha_wi = F(26); const float* mha_bi = F(27);
  const float* mha_wo = F(28); const float* mha_bo = F(29);
  const float* att_w  = F(30);
  const float* ntn_w  = F(31); const float* ntn_v = F(32); const float* ntn_b = F(33);
  const float* fc1_w  = F(34); const float* fc1_b = F(35);
  const float* sc_w   = F(36); const float* sc_b  = F(37);
  float* out = (float*)d_out;

  char* ws = (char*)d_ws;
  const size_t MB = 1 << 20;
  // Edge-conv segment [0, 35MB) -- dead before the MHA phase begins:
  float* xA   = (float*)(ws + 0*MB);        // 8 MB  (16 x 1024 x 128 x 4)
  float* xB   = (float*)(ws + 8*MB);        // 8 MB
  float* zs   = (float*)(ws + 16*MB);       // 8 MB
  float* cvb  = (float*)(ws + 24*MB);       // 8 MB
  int*   idxb = (int*)  (ws + 32*MB);       // 1.25 MB
  float* xxb  = (float*)(ws + 34*MB);       // 64 KB
  float* fuse = (float*)(ws + 35*MB);       // 4 MB  [dies after k_lin]
  // MHA segment aliases the dead edge-conv buffers (stream-sequential, safe):
  float* qkv   = (float*)(ws + 0*MB);       // 12 MB over xA + xB-low   (dead)
  float* plb   = (float*)(ws + 12*MB);      // 4 MB  over xB-high       (dead)
  float* paccb = (float*)(ws + 16*MB);      // 32 MB over zs,cvb,idx,xx,fuse (dead)
  float* attno = (float*)(ws + 48*MB);      // 4 MB fresh
  float* emb   = (float*)(ws + 52*MB);      // 2 MB fresh
  float* pooled= (float*)(ws + 54*MB);      // 2 KB
  (void)ws_size;

  auto knn = [&](const float* xin, int CS, int nch8){
    k_knn<<<BD*64, 256, 0, stream>>>(xin, xxb, idxb, CS, nch8);
  };
  auto phA = [&](const float* xin, int C, int XS, int O, const float* W, const float* bb,
                 const float* gg, const float* be){
    if (O == 64)       k_phaseA<64> <<<BD*32, 256, 0, stream>>>(xin, W, bb, gg, be, zs, cvb, C, XS);
    else if (O == 128) k_phaseA<128><<<BD*32, 256, 0, stream>>>(xin, W, bb, gg, be, zs, cvb, C, XS);
    else               k_phaseA<32> <<<BD*32, 256, 0, stream>>>(xin, W, bb, gg, be, zs, cvb, C, XS);
  };

  for (int part = 0; part < 2; ++part){
    const float* const* Wl = part ? sw : cw;
    const float* const* bl = part ? sb : cb;
    const float* const* gl = part ? sg : cg;
    const float* const* Bl = part ? sB : cB;
    int C0 = part ? 12 : 3;
    int CS0 = part ? 12 : 4;
    // layer 0: C0 -> 64 (both branches at once: 16 batches)
    if (part) k_prep<12,12><<<BD*ND/256, 256, 0, stream>>>(f1, f2, xA, xxb, 3);
    else      k_prep<3, 4> <<<BD*ND/256, 256, 0, stream>>>(f1, f2, xA, xxb, 0);
    knn(xA, CS0, part ? 2 : 1);
    phA(xA, C0, CS0, 64, Wl[0], bl[0], gl[0], Bl[0]);
    k_phaseB<true,true><<<BD*ND/4, 256, 0, stream>>>(zs, cvb, idxb, xB, xxb, 64, 0, 0);
    // layer 1: 64 -> 128 (xx produced by phaseB)
    knn(xB, 64, 8);
    phA(xB, 64, 64, 128, Wl[1], bl[1], gl[1], Bl[1]);
    k_phaseB<true,true><<<BD*ND/4, 256, 0, stream>>>(zs, cvb, idxb, xA, xxb, 128, 0, 0);
    // layer 2: 128 -> 32, written into fuse at column offset (row-major)
    knn(xA, 128, 16);
    phA(xA, 128, 128, 32, Wl[2], bl[2], gl[2], Bl[2]);
    k_phaseB<false,false><<<BD*ND/4, 256, 0, stream>>>(zs, cvb, idxb, fuse, nullptr, 32, 64, part*32);
  }
  // MHA (flash-decode, no-max exp) over all 16 batches
  k_lin<<<BD*32, 256, 0, stream>>>(fuse, mha_wi, mha_bi, qkv);
  k_attn_part<<<BD*4*KSL, 256, 0, stream>>>(qkv, plb, paccb);
  k_attn_comb<<<(BD*8*ND)/256, 256, 0, stream>>>(plb, paccb, attno);
  k_projmean<<<(BD*ND*32)/256, 256, 0, stream>>>(attno, mha_wo, mha_bo, emb);
  // fused attention pool (sout slices are contiguous across the 16 batches)
  k_poolfuse<<<BD, 256, 0, stream>>>(emb, att_w, out + 8, pooled);
  k_head<<<1, 256, 0, stream>>>(pooled, pooled + 256, ntn_w, ntn_v, ntn_b,
                                fc1_w, fc1_b, sc_w, sc_b, out);
}